// Round 1
// baseline (2928.622 us; speedup 1.0000x reference)
//
#include <hip/hip_runtime.h>
#include <math.h>

#define Bn 4096
#define Fn 1536
#define Hn 256
#define Cn 38
#define Kn 7

#define SPLIT 2
#define HCOLS (Bn / SPLIT)   // 2048 columns per half
#define NC 256
#define KT 16
#define MR 16

// ---------- BN param prep (f64): x = feat*A + C ----------
__global__ void k_prep(const float* __restrict__ g, const float* __restrict__ b,
                       const float* __restrict__ m, const float* __restrict__ v,
                       double* __restrict__ A64, double* __restrict__ C64) {
  int f = blockIdx.x * 256 + threadIdx.x;
  if (f < Fn) {
    double rs = 1.0 / sqrt((double)v[f] + 1e-5);
    double a = (double)g[f] * rs;
    A64[f] = a;
    C64[f] = (double)b[f] - (double)m[f] * a;
  }
}

// x32 = BN(features) rounded to f32 (network path input)
__global__ void k_bnx(const float* __restrict__ feat, const double* __restrict__ A64,
                      const double* __restrict__ C64, float* __restrict__ x32) {
  size_t i = (size_t)blockIdx.x * 256 + threadIdx.x;
  int f = (int)(i % Fn);
  x32[i] = (float)fma((double)feat[i], A64[f], C64[f]);
}

// sq[i] = sum_f x64[i][f]^2  (f64)
__global__ void k_rowsq(const float* __restrict__ feat, const double* __restrict__ A64,
                        const double* __restrict__ C64, double* __restrict__ sq) {
  int row = blockIdx.x, tid = threadIdx.x;
  const float* fr = feat + (size_t)row * Fn;
  double s = 0.0;
  for (int f = tid; f < Fn; f += 256) {
    double x = fma((double)fr[f], A64[f], C64[f]);
    s += x * x;
  }
  for (int o = 32; o > 0; o >>= 1) s += __shfl_down(s, o);
  __shared__ double red[4];
  if ((tid & 63) == 0) red[tid >> 6] = s;
  __syncthreads();
  if (tid == 0) sq[row] = red[0] + red[1] + red[2] + red[3];
}

// ---------- fused f64 Gram + per-row top-7 (per column half) ----------
__global__ __launch_bounds__(256) void k_knn(
    const float* __restrict__ feat, const double* __restrict__ A64,
    const double* __restrict__ C64, const double* __restrict__ sq,
    const float* __restrict__ noise,
    double* __restrict__ pd, int* __restrict__ pi) {
  __shared__ double As[KT][MR];            // [kk][row]
  __shared__ double BsDs[NC * (KT + 1)];   // Bs view: [kk*NC+c]; Ds view: [r*(NC+1)+c]
  int tid = threadIdx.x;
  int rb = blockIdx.x >> 1;
  int half = blockIdx.x & 1;
  int row0 = rb * MR;
  int trow = tid >> 6;   // 0..3
  int tcol = tid & 63;   // 0..63
  double bd[Kn]; int bi[Kn];
#pragma unroll
  for (int k = 0; k < Kn; k++) { bd[k] = 1e300; bi[k] = 0; }

  for (int ct0 = 0; ct0 < HCOLS; ct0 += NC) {
    int ct = half * HCOLS + ct0;
    double acc[4][4] = {};
    for (int k0 = 0; k0 < Fn; k0 += KT) {
      { // A tile: 16 rows x 16 k
        int ar = tid & 15, ak = tid >> 4;
        As[ak][ar] = fma((double)feat[(size_t)(row0 + ar) * Fn + k0 + ak],
                         A64[k0 + ak], C64[k0 + ak]);
      }
      { // B tile: 256 cols x 16 k, vectorized row read
        const float* src = feat + (size_t)(ct + tid) * Fn + k0;
#pragma unroll
        for (int q = 0; q < 4; q++) {
          float4 f4 = *reinterpret_cast<const float4*>(src + 4 * q);
          int kb = 4 * q;
          BsDs[(size_t)(kb + 0) * NC + tid] = fma((double)f4.x, A64[k0 + kb + 0], C64[k0 + kb + 0]);
          BsDs[(size_t)(kb + 1) * NC + tid] = fma((double)f4.y, A64[k0 + kb + 1], C64[k0 + kb + 1]);
          BsDs[(size_t)(kb + 2) * NC + tid] = fma((double)f4.z, A64[k0 + kb + 2], C64[k0 + kb + 2]);
          BsDs[(size_t)(kb + 3) * NC + tid] = fma((double)f4.w, A64[k0 + kb + 3], C64[k0 + kb + 3]);
        }
      }
      __syncthreads();
#pragma unroll
      for (int kk = 0; kk < KT; kk++) {
        double a[4], b[4];
#pragma unroll
        for (int i = 0; i < 4; i++) a[i] = As[kk][trow * 4 + i];
#pragma unroll
        for (int j = 0; j < 4; j++) b[j] = BsDs[(size_t)kk * NC + tcol + 64 * j];
#pragma unroll
        for (int i = 0; i < 4; i++)
#pragma unroll
          for (int j = 0; j < 4; j++) acc[i][j] = fma(a[i], b[j], acc[i][j]);
      }
      __syncthreads();
    }
    // distances into Ds (reuses Bs storage; Bs dead after k-loop barrier)
#pragma unroll
    for (int i = 0; i < 4; i++) {
      int r = trow * 4 + i, gr = row0 + r;
      double sqr = sq[gr];
#pragma unroll
      for (int j = 0; j < 4; j++) {
        int c = tcol + 64 * j, gc = ct + c;
        double d2 = sqr + sq[gc] - 2.0 * acc[i][j];
        d2 = d2 > 0.0 ? d2 : 0.0;
        double d = sqrt(d2) + (double)noise[(size_t)gr * Bn + gc] * 1e-6;
        if (gc == gr) d = 1e30;   // exclude self
        BsDs[(size_t)r * (NC + 1) + c] = d;
      }
    }
    __syncthreads();
    if (tid < MR) {
#pragma unroll 1
      for (int c = 0; c < NC; c++) {
        double d = BsDs[(size_t)tid * (NC + 1) + c];
        if (d < bd[Kn - 1]) {
          bd[Kn - 1] = d; bi[Kn - 1] = ct + c;
#pragma unroll
          for (int k = Kn - 1; k > 0; k--) {
            if (bd[k] < bd[k - 1]) {
              double td = bd[k]; bd[k] = bd[k - 1]; bd[k - 1] = td;
              int ti = bi[k]; bi[k] = bi[k - 1]; bi[k - 1] = ti;
            }
          }
        }
      }
    }
    __syncthreads();   // scanners must finish before next tile's Bs overwrite
  }
  if (tid < MR) {
    int row = row0 + tid;
#pragma unroll
    for (int k = 0; k < Kn; k++) {
      pd[((size_t)row * SPLIT + half) * Kn + k] = bd[k];
      pi[((size_t)row * SPLIT + half) * Kn + k] = bi[k];
    }
  }
}

// merge the two halves' sorted top-7 lists
__global__ void k_knnmerge(const double* __restrict__ pd, const int* __restrict__ pi,
                           int* __restrict__ knn) {
  int row = blockIdx.x * 256 + threadIdx.x;
  if (row >= Bn) return;
  const double* d0 = pd + (size_t)row * SPLIT * Kn;
  const double* d1 = d0 + Kn;
  const int* i0 = pi + (size_t)row * SPLIT * Kn;
  const int* i1 = i0 + Kn;
  int a = 0, b = 0;
#pragma unroll
  for (int k = 0; k < Kn; k++) {
    if (d0[a] <= d1[b]) { knn[row * Kn + k] = i0[a]; a++; }
    else                { knn[row * Kn + k] = i1[b]; b++; }
  }
}

// ---------- degree / dinv ----------
__global__ void k_deginit(float* __restrict__ deg) {
  int i = blockIdx.x * 256 + threadIdx.x;
  if (i < Bn) deg[i] = 1.f;   // self loop
}
__global__ void k_degsc(const int* __restrict__ knn, float* __restrict__ deg) {
  int i = blockIdx.x * 256 + threadIdx.x;
  if (i < Bn * Kn) atomicAdd(&deg[knn[i]], 1.f);
}
__global__ void k_dinv(const float* __restrict__ deg, float* __restrict__ dinv) {
  int i = blockIdx.x * 256 + threadIdx.x;
  if (i < Bn) dinv[i] = rsqrtf(deg[i]);
}

// ---------- GCN aggregation ----------
__global__ void k_agginit(const float* __restrict__ h, const float* __restrict__ dinv,
                          const float* __restrict__ bias, float* __restrict__ out) {
  int t = blockIdx.x, f = threadIdx.x;
  float di = dinv[t];
  out[(size_t)t * Hn + f] = di * di * h[(size_t)t * Hn + f] + bias[f];
}
__global__ void k_aggsc(const float* __restrict__ h, const int* __restrict__ knn,
                        const float* __restrict__ dinv, float* __restrict__ out) {
  int s = blockIdx.x, f = threadIdx.x;
  float hv = h[(size_t)s * Hn + f] * dinv[s];
#pragma unroll
  for (int k = 0; k < Kn; k++) {
    int t = knn[s * Kn + k];
    atomicAdd(&out[(size_t)t * Hn + f], dinv[t] * hv);
  }
}
__global__ void k_bnact(float* __restrict__ x, const float* __restrict__ g,
                        const float* __restrict__ b, const float* __restrict__ m,
                        const float* __restrict__ v, int relu) {
  int i = blockIdx.x * 256 + threadIdx.x;
  int c = i & (Hn - 1);
  float val = (x[i] - m[c]) * rsqrtf(v[c] + 1e-5f) * g[c] + b[c];
  x[i] = relu ? fmaxf(val, 0.f) : val;
}

// ---------- generic f32 GEMM, 64x64 tile, two-segment A for concat ----------
// C[M][N] = [A1 | A2] @ Bw ; ep: 0 none, 1 +bias, 2 +bias+relu
__global__ __launch_bounds__(256) void k_gemm(
    const float* __restrict__ A1, int lda1, const float* __restrict__ A2, int lda2, int Ksplit,
    const float* __restrict__ Bw, const float* __restrict__ bias,
    float* __restrict__ C, int M, int N, int K, int ep) {
  __shared__ float As[16][65];
  __shared__ float Bs[16][64];
  int tid = threadIdx.x;
  int n0 = blockIdx.x * 64;
  int row0 = blockIdx.y * 64;
  int tx = tid & 15, ty = tid >> 4;
  float acc[4][4] = {};
  for (int k0 = 0; k0 < K; k0 += 16) {
    int kk = tid & 15, mi = tid >> 4;
#pragma unroll
    for (int p = 0; p < 4; p++) {
      int row = row0 + mi + p * 16;
      int kg = k0 + kk;
      float v = (kg < Ksplit) ? A1[(size_t)row * lda1 + kg]
                              : A2[(size_t)row * lda2 + (kg - Ksplit)];
      As[kk][mi + p * 16] = v;
    }
    int nj = tid & 63, kq = tid >> 6;
#pragma unroll
    for (int p = 0; p < 4; p++) {
      int kb = kq + p * 4;
      int n = n0 + nj;
      Bs[kb][nj] = (n < N) ? Bw[(size_t)(k0 + kb) * N + n] : 0.f;
    }
    __syncthreads();
#pragma unroll
    for (int kk2 = 0; kk2 < 16; kk2++) {
      float a[4], b[4];
#pragma unroll
      for (int i = 0; i < 4; i++) a[i] = As[kk2][ty * 4 + i];
#pragma unroll
      for (int j = 0; j < 4; j++) b[j] = Bs[kk2][tx * 4 + j];
#pragma unroll
      for (int i = 0; i < 4; i++)
#pragma unroll
        for (int j = 0; j < 4; j++) acc[i][j] += a[i] * b[j];
    }
    __syncthreads();
  }
#pragma unroll
  for (int i = 0; i < 4; i++) {
    int row = row0 + ty * 4 + i;
#pragma unroll
    for (int j = 0; j < 4; j++) {
      int n = n0 + tx * 4 + j;
      if (n < N) {
        float v = acc[i][j];
        if (ep >= 1) v += bias[n];
        if (ep == 2) v = fmaxf(v, 0.f);
        C[(size_t)row * N + n] = v;
      }
    }
  }
}

extern "C" void kernel_launch(void* const* d_in, const int* in_sizes, int n_in,
                              void* d_out, int out_size, void* d_ws, size_t ws_size,
                              hipStream_t stream) {
  const float* feat  = (const float*)d_in[0];
  const float* noise = (const float*)d_in[1];
  const float* bnf_g = (const float*)d_in[2];
  const float* bnf_b = (const float*)d_in[3];
  const float* bnf_m = (const float*)d_in[4];
  const float* bnf_v = (const float*)d_in[5];
  const float* W1 = (const float*)d_in[6];
  const float* b1 = (const float*)d_in[7];
  const float* W2 = (const float*)d_in[8];
  const float* b2 = (const float*)d_in[9];
  const float* W3 = (const float*)d_in[10];
  const float* b3 = (const float*)d_in[11];
  const float* bn1_g = (const float*)d_in[12];
  const float* bn1_b = (const float*)d_in[13];
  const float* bn1_m = (const float*)d_in[14];
  const float* bn1_v = (const float*)d_in[15];
  const float* bn2_g = (const float*)d_in[16];
  const float* bn2_b = (const float*)d_in[17];
  const float* bn2_m = (const float*)d_in[18];
  const float* bn2_v = (const float*)d_in[19];
  const float* bn3_g = (const float*)d_in[20];
  const float* bn3_b = (const float*)d_in[21];
  const float* bn3_m = (const float*)d_in[22];
  const float* bn3_v = (const float*)d_in[23];
  const float* Wc1 = (const float*)d_in[24];
  const float* bc1 = (const float*)d_in[25];
  const float* Wc2 = (const float*)d_in[26];
  const float* bc2 = (const float*)d_in[27];
  float* outp = (float*)d_out;

  char* w = (char*)d_ws;
  size_t off = 0;
  auto alloc = [&](size_t n) { void* p = w + off; off = (off + n + 255) & ~(size_t)255; return p; };
  float*  x32  = (float*) alloc((size_t)Bn * Fn * 4);
  double* A64  = (double*)alloc(Fn * 8);
  double* C64  = (double*)alloc(Fn * 8);
  double* sq   = (double*)alloc(Bn * 8);
  double* pd   = (double*)alloc((size_t)Bn * SPLIT * Kn * 8);
  int*    pi   = (int*)   alloc((size_t)Bn * SPLIT * Kn * 4);
  int*    knn  = (int*)   alloc((size_t)Bn * Kn * 4);
  float*  deg  = (float*) alloc(Bn * 4);
  float*  dinv = (float*) alloc(Bn * 4);
  float*  g1   = (float*) alloc((size_t)Bn * Hn * 4);
  float*  g2   = (float*) alloc((size_t)Bn * Hn * 4);
  float*  hid  = (float*) alloc((size_t)Bn * 128 * 4);
  (void)ws_size; (void)in_sizes; (void)n_in; (void)out_size;

  k_prep<<<(Fn + 255) / 256, 256, 0, stream>>>(bnf_g, bnf_b, bnf_m, bnf_v, A64, C64);
  k_bnx<<<(Bn * Fn) / 256, 256, 0, stream>>>(feat, A64, C64, x32);
  k_rowsq<<<Bn, 256, 0, stream>>>(feat, A64, C64, sq);
  k_knn<<<(Bn / MR) * SPLIT, 256, 0, stream>>>(feat, A64, C64, sq, noise, pd, pi);
  k_knnmerge<<<(Bn + 255) / 256, 256, 0, stream>>>(pd, pi, knn);
  k_deginit<<<(Bn + 255) / 256, 256, 0, stream>>>(deg);
  k_degsc<<<(Bn * Kn + 255) / 256, 256, 0, stream>>>(knn, deg);
  k_dinv<<<(Bn + 255) / 256, 256, 0, stream>>>(deg, dinv);

  dim3 gg1((Hn + 63) / 64, Bn / 64);
  // layer 1
  k_gemm<<<gg1, 256, 0, stream>>>(x32, Fn, x32, Fn, Fn, W1, nullptr, g1, Bn, Hn, Fn, 0);
  k_agginit<<<Bn, Hn, 0, stream>>>(g1, dinv, b1, g2);
  k_aggsc<<<Bn, Hn, 0, stream>>>(g1, knn, dinv, g2);
  k_bnact<<<(Bn * Hn) / 256, 256, 0, stream>>>(g2, bn1_g, bn1_b, bn1_m, bn1_v, 1);
  // layer 2
  k_gemm<<<gg1, 256, 0, stream>>>(g2, Hn, g2, Hn, Hn, W2, nullptr, g1, Bn, Hn, Hn, 0);
  k_agginit<<<Bn, Hn, 0, stream>>>(g1, dinv, b2, g2);
  k_aggsc<<<Bn, Hn, 0, stream>>>(g1, knn, dinv, g2);
  k_bnact<<<(Bn * Hn) / 256, 256, 0, stream>>>(g2, bn2_g, bn2_b, bn2_m, bn2_v, 1);
  // layer 3
  k_gemm<<<gg1, 256, 0, stream>>>(g2, Hn, g2, Hn, Hn, W3, nullptr, g1, Bn, Hn, Hn, 0);
  k_agginit<<<Bn, Hn, 0, stream>>>(g1, dinv, b3, g2);
  k_aggsc<<<Bn, Hn, 0, stream>>>(g1, knn, dinv, g2);
  k_bnact<<<(Bn * Hn) / 256, 256, 0, stream>>>(g2, bn3_g, bn3_b, bn3_m, bn3_v, 0);
  // classifier: comb = [h3 | x_orig]
  dim3 gc1((128 + 63) / 64, Bn / 64);
  k_gemm<<<gc1, 256, 0, stream>>>(g2, Hn, x32, Fn, Hn, Wc1, bc1, hid, Bn, 128, Hn + Fn, 2);
  dim3 gc2((Cn + 63) / 64, Bn / 64);
  k_gemm<<<gc2, 256, 0, stream>>>(hid, 128, hid, 128, 128, Wc2, bc2, outp, Bn, Cn, 128, 1);
}

// Round 2
// 981.598 us; speedup vs baseline: 2.9835x; 2.9835x over previous
//
#include <hip/hip_runtime.h>
#include <hip/hip_bf16.h>
#include <math.h>

#define Bn 4096
#define Fn 1536
#define Hn 256
#define Cn 38
#define Kn 7
#define GBK 64

typedef __attribute__((ext_vector_type(8))) short short8;
typedef __attribute__((ext_vector_type(4))) float f32x4;
typedef unsigned long long u64;
typedef unsigned int u32;
typedef unsigned short u16;

__device__ __forceinline__ void gld16(const void* g, void* l) {
  __builtin_amdgcn_global_load_lds((const __attribute__((address_space(1))) unsigned int*)g,
                                   (__attribute__((address_space(3))) unsigned int*)l, 16, 0, 0);
}

// ---------- BN param prep (f64): x = feat*A + C ----------
__global__ void k_prep(const float* __restrict__ g, const float* __restrict__ b,
                       const float* __restrict__ m, const float* __restrict__ v,
                       double* __restrict__ A64, double* __restrict__ C64) {
  int f = blockIdx.x * 256 + threadIdx.x;
  if (f < Fn) {
    double rs = 1.0 / sqrt((double)v[f] + 1e-5);
    double a = (double)g[f] * rs;
    A64[f] = a;
    C64[f] = (double)b[f] - (double)m[f] * a;
  }
}

// x32 = BN(features) f32; Ah/Al = bf16 hi/lo split of x32
__global__ void k_bnsplit(const float* __restrict__ feat, const double* __restrict__ A64,
                          const double* __restrict__ C64, float* __restrict__ x32,
                          u16* __restrict__ Ah, u16* __restrict__ Al) {
  size_t i = (size_t)blockIdx.x * 256 + threadIdx.x;
  int f = (int)(i % Fn);
  float x = (float)fma((double)feat[i], A64[f], C64[f]);
  x32[i] = x;
  __hip_bfloat16 h = __float2bfloat16(x);
  float hf = __bfloat162float(h);
  __hip_bfloat16 lo = __float2bfloat16(x - hf);
  Ah[i] = *reinterpret_cast<u16*>(&h);
  Al[i] = *reinterpret_cast<u16*>(&lo);
}

// sq[i] = sum_f x64[i][f]^2  (f64)
__global__ void k_rowsq(const float* __restrict__ feat, const double* __restrict__ A64,
                        const double* __restrict__ C64, double* __restrict__ sq) {
  int row = blockIdx.x, tid = threadIdx.x;
  const float* fr = feat + (size_t)row * Fn;
  double s = 0.0;
  for (int f = tid; f < Fn; f += 256) {
    double x = fma((double)fr[f], A64[f], C64[f]);
    s += x * x;
  }
  for (int o = 32; o > 0; o >>= 1) s += __shfl_down(s, o);
  __shared__ double red[4];
  if ((tid & 63) == 0) red[tid >> 6] = s;
  __syncthreads();
  if (tid == 0) sq[row] = red[0] + red[1] + red[2] + red[3];
}

// ---------- bf16-split MFMA Gram + fused per-row/64-col top-8 ----------
__global__ __launch_bounds__(256) void k_gram(
    const u16* __restrict__ Ah, const u16* __restrict__ Al,
    const double* __restrict__ sq, u64* __restrict__ part) {
  __shared__ union {
    u16 t[4][128 * GBK];   // tiles: ah, al, bh, bl   (16 KB each, swizzled layout)
    float c[128 * 129];    // C tile (epilogue)
  } lds;
  const int tid = threadIdx.x;
  const int w = tid >> 6, l = tid & 63;
  const int bi = blockIdx.y, bj = blockIdx.x;
  const int rA0 = bi * 128, rB0 = bj * 128;

  // staging mapping: seg=0..15 (1KB each), row = seg*8 + l/8, colbyte = (l&7)*16
  const int s_sub = l >> 3;
  const int s_cb = (l & 7) * 16;
  // fragment mapping
  const int fr = l & 15;
  const int fk2 = (l >> 4) * 16;   // k byte base within 64B half

  const u16* mats[4] = { Ah + (size_t)rA0 * Fn, Al + (size_t)rA0 * Fn,
                         Ah + (size_t)rB0 * Fn, Al + (size_t)rB0 * Fn };

  f32x4 acc[4][4];
  const f32x4 fz = {0.f, 0.f, 0.f, 0.f};
#pragma unroll
  for (int i = 0; i < 4; i++)
#pragma unroll
    for (int j = 0; j < 4; j++) acc[i][j] = fz;

  auto stage = [&](int k0) {
#pragma unroll
    for (int mm = 0; mm < 4; mm++) {
      const u16* src = mats[mm];
#pragma unroll
      for (int q = 0; q < 4; q++) {
        int seg = w * 4 + q;
        int row = seg * 8 + s_sub;
        int scb = s_cb ^ ((row & 7) << 4);   // pre-swizzled global source
        gld16(src + (size_t)row * Fn + k0 + (scb >> 1),
              (char*)&lds.t[mm][0] + seg * 1024);  // +lane*16 by HW
      }
    }
  };

  stage(0);
  const int NT = Fn / GBK;
  for (int kt = 0; kt < NT; kt++) {
    __syncthreads();
#pragma unroll
    for (int kh = 0; kh < 2; kh++) {
      short8 fa[2][4], fb[2][4];
#pragma unroll
      for (int i = 0; i < 4; i++) {
        int ar = (w >> 1) * 64 + i * 16 + fr;
        int kb = (kh * 64 + fk2) ^ ((ar & 7) << 4);
        fa[0][i] = *reinterpret_cast<const short8*>((const char*)&lds.t[0][0] + ar * 128 + kb);
        fa[1][i] = *reinterpret_cast<const short8*>((const char*)&lds.t[1][0] + ar * 128 + kb);
        int br = (w & 1) * 64 + i * 16 + fr;
        int kbb = (kh * 64 + fk2) ^ ((br & 7) << 4);
        fb[0][i] = *reinterpret_cast<const short8*>((const char*)&lds.t[2][0] + br * 128 + kbb);
        fb[1][i] = *reinterpret_cast<const short8*>((const char*)&lds.t[3][0] + br * 128 + kbb);
      }
#pragma unroll
      for (int i = 0; i < 4; i++)
#pragma unroll
        for (int j = 0; j < 4; j++) {
          acc[i][j] = __builtin_amdgcn_mfma_f32_16x16x32_bf16(fa[1][i], fb[0][j], acc[i][j], 0, 0, 0);
          acc[i][j] = __builtin_amdgcn_mfma_f32_16x16x32_bf16(fa[0][i], fb[1][j], acc[i][j], 0, 0, 0);
          acc[i][j] = __builtin_amdgcn_mfma_f32_16x16x32_bf16(fa[0][i], fb[0][j], acc[i][j], 0, 0, 0);
        }
    }
    __syncthreads();
    if (kt + 1 < NT) stage((kt + 1) * GBK);
  }

  // epilogue: C tile to LDS (tiles are dead; all reads drained at final barrier)
#pragma unroll
  for (int i = 0; i < 4; i++) {
    int r0 = (w >> 1) * 64 + i * 16 + (l >> 4) * 4;
#pragma unroll
    for (int j = 0; j < 4; j++) {
      int c0 = (w & 1) * 64 + j * 16 + (l & 15);
#pragma unroll
      for (int g = 0; g < 4; g++)
        lds.c[(r0 + g) * 129 + c0] = acc[i][j][g];
    }
  }
  __syncthreads();

  // selection: 2 threads per row, each scans 64 cols -> top-8 packed (d2bits<<32 | idx)
  int r = tid >> 1, h = tid & 1;
  int grow = rA0 + r;
  float sqr = (float)sq[grow];
  u64 top[8];
#pragma unroll
  for (int k = 0; k < 8; k++) top[k] = ~0ull;
#pragma unroll 1
  for (int c = 0; c < 64; c++) {
    int cc = h * 64 + c;
    int gc = rB0 + cc;
    if (gc == grow) continue;
    float g = lds.c[r * 129 + cc];
    float d2 = fmaxf(sqr + (float)sq[gc] - 2.f * g, 0.f);
    u64 key = ((u64)__float_as_uint(d2) << 32) | (u32)gc;
    if (key < top[7]) {
      top[7] = key;
#pragma unroll
      for (int k = 7; k > 0; k--)
        if (top[k] < top[k - 1]) { u64 tmp = top[k]; top[k] = top[k - 1]; top[k - 1] = tmp; }
    }
  }
  u64* dst = part + ((size_t)grow * 64 + (size_t)(bj * 2 + h)) * 8;
#pragma unroll
  for (int k = 0; k < 8; k++) dst[k] = top[k];
}

// merge 512 partial candidates per row -> top-16 approx candidates
__global__ __launch_bounds__(256) void k_candmerge(const u64* __restrict__ part,
                                                   int* __restrict__ cand) {
  int row = blockIdx.x * 4 + (threadIdx.x >> 6);
  int l = threadIdx.x & 63;
  const u64* p = part + (size_t)row * 512 + (size_t)l * 8;
  u64 e[8];
#pragma unroll
  for (int k = 0; k < 8; k++) e[k] = p[k];
#pragma unroll 1
  for (int rnd = 0; rnd < 16; rnd++) {
    u64 m = e[0];
#pragma unroll
    for (int k = 1; k < 8; k++) m = e[k] < m ? e[k] : m;
#pragma unroll
    for (int off = 32; off; off >>= 1) {
      u64 o = __shfl_xor(m, off);
      m = o < m ? o : m;
    }
    if (l == 0) cand[row * 16 + rnd] = (int)(u32)m;
#pragma unroll
    for (int k = 0; k < 8; k++)
      if (e[k] == m) e[k] = ~0ull;
  }
}

// exact f64 re-rank of 16 candidates (+ noise tie-break) -> knn[row][7]
__global__ __launch_bounds__(256) void k_rerank(
    const float* __restrict__ feat, const double* __restrict__ A64,
    const double* __restrict__ C64, const double* __restrict__ sq,
    const float* __restrict__ noise, const int* __restrict__ cand,
    int* __restrict__ knn) {
  int row = blockIdx.x;
  int w = threadIdx.x >> 6, l = threadIdx.x & 63;
  __shared__ double xrow[Fn];
  __shared__ double dots[16];
  for (int e = threadIdx.x; e < Fn; e += 256)
    xrow[e] = fma((double)feat[(size_t)row * Fn + e], A64[e], C64[e]);
  __syncthreads();
  for (int m = w; m < 16; m += 4) {
    int c = cand[row * 16 + m];
    const float* fc = feat + (size_t)c * Fn;
    double s = 0.0;
    for (int e = l; e < Fn; e += 64) {
      double xj = fma((double)fc[e], A64[e], C64[e]);
      s = fma(xrow[e], xj, s);
    }
#pragma unroll
    for (int off = 32; off; off >>= 1) s += __shfl_xor(s, off);
    if (l == 0) dots[m] = s;
  }
  __syncthreads();
  if (threadIdx.x == 0) {
    double sr = sq[row];
    double bd[Kn]; int bi7[Kn];
#pragma unroll
    for (int k = 0; k < Kn; k++) { bd[k] = 1e300; bi7[k] = 0; }
#pragma unroll 1
    for (int m = 0; m < 16; m++) {
      int c = cand[row * 16 + m];
      double d2 = sr + sq[c] - 2.0 * dots[m];
      d2 = d2 > 0.0 ? d2 : 0.0;
      double d = sqrt(d2) + (double)noise[(size_t)row * Bn + c] * 1e-6;
      if (d < bd[Kn - 1]) {
        bd[Kn - 1] = d; bi7[Kn - 1] = c;
#pragma unroll
        for (int k = Kn - 1; k > 0; k--)
          if (bd[k] < bd[k - 1]) {
            double td = bd[k]; bd[k] = bd[k - 1]; bd[k - 1] = td;
            int ti = bi7[k]; bi7[k] = bi7[k - 1]; bi7[k - 1] = ti;
          }
      }
    }
#pragma unroll
    for (int k = 0; k < Kn; k++) knn[row * Kn + k] = bi7[k];
  }
}

// ---------- degree / dinv ----------
__global__ void k_deginit(float* __restrict__ deg) {
  int i = blockIdx.x * 256 + threadIdx.x;
  if (i < Bn) deg[i] = 1.f;
}
__global__ void k_degsc(const int* __restrict__ knn, float* __restrict__ deg) {
  int i = blockIdx.x * 256 + threadIdx.x;
  if (i < Bn * Kn) atomicAdd(&deg[knn[i]], 1.f);
}
__global__ void k_dinv(const float* __restrict__ deg, float* __restrict__ dinv) {
  int i = blockIdx.x * 256 + threadIdx.x;
  if (i < Bn) dinv[i] = rsqrtf(deg[i]);
}

// ---------- GCN aggregation ----------
__global__ void k_agginit(const float* __restrict__ h, const float* __restrict__ dinv,
                          const float* __restrict__ bias, float* __restrict__ out) {
  int t = blockIdx.x, f = threadIdx.x;
  float di = dinv[t];
  out[(size_t)t * Hn + f] = di * di * h[(size_t)t * Hn + f] + bias[f];
}
__global__ void k_aggsc(const float* __restrict__ h, const int* __restrict__ knn,
                        const float* __restrict__ dinv, float* __restrict__ out) {
  int s = blockIdx.x, f = threadIdx.x;
  float hv = h[(size_t)s * Hn + f] * dinv[s];
#pragma unroll
  for (int k = 0; k < Kn; k++) {
    int t = knn[s * Kn + k];
    atomicAdd(&out[(size_t)t * Hn + f], dinv[t] * hv);
  }
}
__global__ void k_bnact(float* __restrict__ x, const float* __restrict__ g,
                        const float* __restrict__ b, const float* __restrict__ m,
                        const float* __restrict__ v, int relu) {
  int i = blockIdx.x * 256 + threadIdx.x;
  int c = i & (Hn - 1);
  float val = (x[i] - m[c]) * rsqrtf(v[c] + 1e-5f) * g[c] + b[c];
  x[i] = relu ? fmaxf(val, 0.f) : val;
}

// ---------- generic f32 GEMM, 64x64 tile, two-segment A for concat ----------
__global__ __launch_bounds__(256) void k_gemm(
    const float* __restrict__ A1, int lda1, const float* __restrict__ A2, int lda2, int Ksplit,
    const float* __restrict__ Bw, const float* __restrict__ bias,
    float* __restrict__ C, int M, int N, int K, int ep) {
  __shared__ float As[16][65];
  __shared__ float Bs[16][64];
  int tid = threadIdx.x;
  int n0 = blockIdx.x * 64;
  int row0 = blockIdx.y * 64;
  int tx = tid & 15, ty = tid >> 4;
  float acc[4][4] = {};
  for (int k0 = 0; k0 < K; k0 += 16) {
    int kk = tid & 15, mi = tid >> 4;
#pragma unroll
    for (int p = 0; p < 4; p++) {
      int row = row0 + mi + p * 16;
      int kg = k0 + kk;
      float v = (kg < Ksplit) ? A1[(size_t)row * lda1 + kg]
                              : A2[(size_t)row * lda2 + (kg - Ksplit)];
      As[kk][mi + p * 16] = v;
    }
    int nj = tid & 63, kq = tid >> 6;
#pragma unroll
    for (int p = 0; p < 4; p++) {
      int kb = kq + p * 4;
      int n = n0 + nj;
      Bs[kb][nj] = (n < N) ? Bw[(size_t)(k0 + kb) * N + n] : 0.f;
    }
    __syncthreads();
#pragma unroll
    for (int kk2 = 0; kk2 < 16; kk2++) {
      float a[4], b[4];
#pragma unroll
      for (int i = 0; i < 4; i++) a[i] = As[kk2][ty * 4 + i];
#pragma unroll
      for (int j = 0; j < 4; j++) b[j] = Bs[kk2][tx * 4 + j];
#pragma unroll
      for (int i = 0; i < 4; i++)
#pragma unroll
        for (int j = 0; j < 4; j++) acc[i][j] += a[i] * b[j];
    }
    __syncthreads();
  }
#pragma unroll
  for (int i = 0; i < 4; i++) {
    int row = row0 + ty * 4 + i;
#pragma unroll
    for (int j = 0; j < 4; j++) {
      int n = n0 + tx * 4 + j;
      if (n < N) {
        float v = acc[i][j];
        if (ep >= 1) v += bias[n];
        if (ep == 2) v = fmaxf(v, 0.f);
        C[(size_t)row * N + n] = v;
      }
    }
  }
}

extern "C" void kernel_launch(void* const* d_in, const int* in_sizes, int n_in,
                              void* d_out, int out_size, void* d_ws, size_t ws_size,
                              hipStream_t stream) {
  const float* feat  = (const float*)d_in[0];
  const float* noise = (const float*)d_in[1];
  const float* bnf_g = (const float*)d_in[2];
  const float* bnf_b = (const float*)d_in[3];
  const float* bnf_m = (const float*)d_in[4];
  const float* bnf_v = (const float*)d_in[5];
  const float* W1 = (const float*)d_in[6];
  const float* b1 = (const float*)d_in[7];
  const float* W2 = (const float*)d_in[8];
  const float* b2 = (const float*)d_in[9];
  const float* W3 = (const float*)d_in[10];
  const float* b3 = (const float*)d_in[11];
  const float* bn1_g = (const float*)d_in[12];
  const float* bn1_b = (const float*)d_in[13];
  const float* bn1_m = (const float*)d_in[14];
  const float* bn1_v = (const float*)d_in[15];
  const float* bn2_g = (const float*)d_in[16];
  const float* bn2_b = (const float*)d_in[17];
  const float* bn2_m = (const float*)d_in[18];
  const float* bn2_v = (const float*)d_in[19];
  const float* bn3_g = (const float*)d_in[20];
  const float* bn3_b = (const float*)d_in[21];
  const float* bn3_m = (const float*)d_in[22];
  const float* bn3_v = (const float*)d_in[23];
  const float* Wc1 = (const float*)d_in[24];
  const float* bc1 = (const float*)d_in[25];
  const float* Wc2 = (const float*)d_in[26];
  const float* bc2 = (const float*)d_in[27];
  float* outp = (float*)d_out;

  char* w = (char*)d_ws;
  size_t off = 0;
  auto alloc = [&](size_t n) { void* p = w + off; off = (off + n + 255) & ~(size_t)255; return p; };
  float*  x32  = (float*) alloc((size_t)Bn * Fn * 4);
  u16*    Ahb  = (u16*)   alloc((size_t)Bn * Fn * 2);
  u16*    Alb  = (u16*)   alloc((size_t)Bn * Fn * 2);
  double* A64  = (double*)alloc(Fn * 8);
  double* C64  = (double*)alloc(Fn * 8);
  double* sq   = (double*)alloc(Bn * 8);
  u64*    part = (u64*)   alloc((size_t)Bn * 64 * 8 * 8);
  int*    cand = (int*)   alloc((size_t)Bn * 16 * 4);
  int*    knn  = (int*)   alloc((size_t)Bn * Kn * 4);
  float*  deg  = (float*) alloc(Bn * 4);
  float*  dinv = (float*) alloc(Bn * 4);
  float*  g1   = (float*) alloc((size_t)Bn * Hn * 4);
  float*  g2   = (float*) alloc((size_t)Bn * Hn * 4);
  float*  hid  = (float*) alloc((size_t)Bn * 128 * 4);
  (void)ws_size; (void)in_sizes; (void)n_in; (void)out_size;

  k_prep<<<(Fn + 255) / 256, 256, 0, stream>>>(bnf_g, bnf_b, bnf_m, bnf_v, A64, C64);
  k_bnsplit<<<(Bn * Fn) / 256, 256, 0, stream>>>(feat, A64, C64, x32, Ahb, Alb);
  k_rowsq<<<Bn, 256, 0, stream>>>(feat, A64, C64, sq);
  k_gram<<<dim3(32, 32), 256, 0, stream>>>(Ahb, Alb, sq, part);
  k_candmerge<<<Bn / 4, 256, 0, stream>>>(part, cand);
  k_rerank<<<Bn, 256, 0, stream>>>(feat, A64, C64, sq, noise, cand, knn);
  k_deginit<<<(Bn + 255) / 256, 256, 0, stream>>>(deg);
  k_degsc<<<(Bn * Kn + 255) / 256, 256, 0, stream>>>(knn, deg);
  k_dinv<<<(Bn + 255) / 256, 256, 0, stream>>>(deg, dinv);

  dim3 gg1((Hn + 63) / 64, Bn / 64);
  // layer 1
  k_gemm<<<gg1, 256, 0, stream>>>(x32, Fn, x32, Fn, Fn, W1, nullptr, g1, Bn, Hn, Fn, 0);
  k_agginit<<<Bn, Hn, 0, stream>>>(g1, dinv, b1, g2);
  k_aggsc<<<Bn, Hn, 0, stream>>>(g1, knn, dinv, g2);
  k_bnact<<<(Bn * Hn) / 256, 256, 0, stream>>>(g2, bn1_g, bn1_b, bn1_m, bn1_v, 1);
  // layer 2
  k_gemm<<<gg1, 256, 0, stream>>>(g2, Hn, g2, Hn, Hn, W2, nullptr, g1, Bn, Hn, Hn, 0);
  k_agginit<<<Bn, Hn, 0, stream>>>(g1, dinv, b2, g2);
  k_aggsc<<<Bn, Hn, 0, stream>>>(g1, knn, dinv, g2);
  k_bnact<<<(Bn * Hn) / 256, 256, 0, stream>>>(g2, bn2_g, bn2_b, bn2_m, bn2_v, 1);
  // layer 3
  k_gemm<<<gg1, 256, 0, stream>>>(g2, Hn, g2, Hn, Hn, W3, nullptr, g1, Bn, Hn, Hn, 0);
  k_agginit<<<Bn, Hn, 0, stream>>>(g1, dinv, b3, g2);
  k_aggsc<<<Bn, Hn, 0, stream>>>(g1, knn, dinv, g2);
  k_bnact<<<(Bn * Hn) / 256, 256, 0, stream>>>(g2, bn3_g, bn3_b, bn3_m, bn3_v, 0);
  // classifier: comb = [h3 | x_orig]
  dim3 gc1((128 + 63) / 64, Bn / 64);
  k_gemm<<<gc1, 256, 0, stream>>>(g2, Hn, x32, Fn, Hn, Wc1, bc1, hid, Bn, 128, Hn + Fn, 2);
  dim3 gc2((Cn + 63) / 64, Bn / 64);
  k_gemm<<<gc2, 256, 0, stream>>>(hid, 128, hid, 128, 128, Wc2, bc2, outp, Bn, Cn, 128, 1);
}

// Round 4
// 764.775 us; speedup vs baseline: 3.8294x; 1.2835x over previous
//
#include <hip/hip_runtime.h>
#include <hip/hip_bf16.h>
#include <math.h>

#define Bn 4096
#define Fn 1536
#define Hn 256
#define Cn 38
#define Kn 7
#define GBK 64

typedef __attribute__((ext_vector_type(8))) short short8;
typedef __attribute__((ext_vector_type(4))) float f32x4;
typedef unsigned long long u64;
typedef unsigned int u32;
typedef unsigned short u16;

__device__ __forceinline__ void gld16(const void* g, void* l) {
  __builtin_amdgcn_global_load_lds((const __attribute__((address_space(1))) unsigned int*)g,
                                   (__attribute__((address_space(3))) unsigned int*)l, 16, 0, 0);
}

// ---------- BN param prep (f64): x = feat*A + C ----------
__global__ void k_prep(const float* __restrict__ g, const float* __restrict__ b,
                       const float* __restrict__ m, const float* __restrict__ v,
                       double* __restrict__ A64, double* __restrict__ C64) {
  int f = blockIdx.x * 256 + threadIdx.x;
  if (f < Fn) {
    double rs = 1.0 / sqrt((double)v[f] + 1e-5);
    double a = (double)g[f] * rs;
    A64[f] = a;
    C64[f] = (double)b[f] - (double)m[f] * a;
  }
}

// Ah/Al = bf16 hi/lo split of BN(features)
__global__ void k_bnsplit(const float* __restrict__ feat, const double* __restrict__ A64,
                          const double* __restrict__ C64,
                          u16* __restrict__ Ah, u16* __restrict__ Al) {
  size_t i = (size_t)blockIdx.x * 256 + threadIdx.x;
  int f = (int)(i % Fn);
  float x = (float)fma((double)feat[i], A64[f], C64[f]);
  __hip_bfloat16 h = __float2bfloat16(x);
  float hf = __bfloat162float(h);
  __hip_bfloat16 lo = __float2bfloat16(x - hf);
  Ah[i] = *reinterpret_cast<u16*>(&h);
  Al[i] = *reinterpret_cast<u16*>(&lo);
}

// sq[i] = sum_f x64[i][f]^2  (f64)
__global__ void k_rowsq(const float* __restrict__ feat, const double* __restrict__ A64,
                        const double* __restrict__ C64, double* __restrict__ sq) {
  int row = blockIdx.x, tid = threadIdx.x;
  const float* fr = feat + (size_t)row * Fn;
  double s = 0.0;
  for (int f = tid; f < Fn; f += 256) {
    double x = fma((double)fr[f], A64[f], C64[f]);
    s += x * x;
  }
  for (int o = 32; o > 0; o >>= 1) s += __shfl_down(s, o);
  __shared__ double red[4];
  if ((tid & 63) == 0) red[tid >> 6] = s;
  __syncthreads();
  if (tid == 0) sq[row] = red[0] + red[1] + red[2] + red[3];
}

// transpose + hi/lo split weights: W[K×N] f32 -> Wt[N×K] bf16 hi/lo
__global__ void k_wsplit(const float* __restrict__ W, int K, int N,
                         u16* __restrict__ Wth, u16* __restrict__ Wtl) {
  __shared__ float t[32][33];
  int k0 = blockIdx.y * 32, n0 = blockIdx.x * 32;
  int tx = threadIdx.x & 31, ty = threadIdx.x >> 5;  // ty 0..7
  for (int p = 0; p < 32; p += 8) {
    int k = k0 + ty + p, n = n0 + tx;
    t[ty + p][tx] = (k < K && n < N) ? W[(size_t)k * N + n] : 0.f;
  }
  __syncthreads();
  for (int p = 0; p < 32; p += 8) {
    int n = n0 + ty + p, k = k0 + tx;
    if (n < N && k < K) {
      float x = t[tx][ty + p];
      __hip_bfloat16 h = __float2bfloat16(x);
      float hf = __bfloat162float(h);
      __hip_bfloat16 lo = __float2bfloat16(x - hf);
      Wth[(size_t)n * K + k] = *reinterpret_cast<u16*>(&h);
      Wtl[(size_t)n * K + k] = *reinterpret_cast<u16*>(&lo);
    }
  }
}

// ---------- bf16-split MFMA Gram + fused per-row/64-col top-8 ----------
// LDS tiles are k-major: addr = kq*2048 + row*16 (+b), kq = 16B chunk of the 128B row.
__global__ __launch_bounds__(256) void k_gram(
    const u16* __restrict__ Ah, const u16* __restrict__ Al,
    const double* __restrict__ sq, u64* __restrict__ part) {
  __shared__ union {
    u16 t[4][8192];        // tiles: ah, al, bh, bl (16 KB each, k-major)
    float c[128 * 129];    // C tile (epilogue)
  } lds;
  const int tid = threadIdx.x;
  const int w = tid >> 6, l = tid & 63;
  const int bi = blockIdx.y, bj = blockIdx.x;
  const int rA0 = bi * 128, rB0 = bj * 128;
  const int fr = l & 15;
  const int fq = l >> 4;          // k-quarter 0..3

  const u16* mats[4] = { Ah + (size_t)rA0 * Fn, Al + (size_t)rA0 * Fn,
                         Ah + (size_t)rB0 * Fn, Al + (size_t)rB0 * Fn };

  f32x4 acc[4][4];
  const f32x4 fz = {0.f, 0.f, 0.f, 0.f};
#pragma unroll
  for (int i = 0; i < 4; i++)
#pragma unroll
    for (int j = 0; j < 4; j++) acc[i][j] = fz;

  auto stage = [&](int k0) {
#pragma unroll
    for (int mm = 0; mm < 4; mm++) {
      const u16* src = mats[mm];
#pragma unroll
      for (int q = 0; q < 4; q++) {
        int s = w * 4 + q;                  // seg 0..15: kq = s>>1, rowhalf = s&1
        int row = (s & 1) * 64 + l;
        gld16(src + (size_t)row * Fn + k0 + (s >> 1) * 8,
              (char*)&lds.t[mm][0] + s * 1024);   // + lane*16 by HW
      }
    }
  };

  stage(0);
  const int NT = Fn / GBK;
  for (int kt = 0; kt < NT; kt++) {
    __syncthreads();
#pragma unroll
    for (int kh = 0; kh < 2; kh++) {
      const int kb = (kh * 4 + fq) * 2048;   // 128 rows/tile -> 2048B per k-chunk
      short8 fa[2][4], fb[2][4];
#pragma unroll
      for (int i = 0; i < 4; i++) {
        int ar = (w >> 1) * 64 + i * 16 + fr;
        fa[0][i] = *reinterpret_cast<const short8*>((const char*)&lds.t[0][0] + kb + ar * 16);
        fa[1][i] = *reinterpret_cast<const short8*>((const char*)&lds.t[1][0] + kb + ar * 16);
        int br = (w & 1) * 64 + i * 16 + fr;
        fb[0][i] = *reinterpret_cast<const short8*>((const char*)&lds.t[2][0] + kb + br * 16);
        fb[1][i] = *reinterpret_cast<const short8*>((const char*)&lds.t[3][0] + kb + br * 16);
      }
#pragma unroll
      for (int i = 0; i < 4; i++)
#pragma unroll
        for (int j = 0; j < 4; j++) {
          acc[i][j] = __builtin_amdgcn_mfma_f32_16x16x32_bf16(fa[1][i], fb[0][j], acc[i][j], 0, 0, 0);
          acc[i][j] = __builtin_amdgcn_mfma_f32_16x16x32_bf16(fa[0][i], fb[1][j], acc[i][j], 0, 0, 0);
          acc[i][j] = __builtin_amdgcn_mfma_f32_16x16x32_bf16(fa[0][i], fb[0][j], acc[i][j], 0, 0, 0);
        }
    }
    __syncthreads();
    if (kt + 1 < NT) stage((kt + 1) * GBK);
  }

  // epilogue: C tile to LDS
#pragma unroll
  for (int i = 0; i < 4; i++) {
    int r0 = (w >> 1) * 64 + i * 16 + fq * 4;
#pragma unroll
    for (int j = 0; j < 4; j++) {
      int c0 = (w & 1) * 64 + j * 16 + fr;
#pragma unroll
      for (int g = 0; g < 4; g++)
        lds.c[(r0 + g) * 129 + c0] = acc[i][j][g];
    }
  }
  __syncthreads();

  // selection: 2 threads per row, each scans 64 cols -> top-8 packed (d2bits<<32 | idx)
  int r = tid >> 1, h = tid & 1;
  int grow = rA0 + r;
  float sqr = (float)sq[grow];
  u64 top[8];
#pragma unroll
  for (int k = 0; k < 8; k++) top[k] = ~0ull;
#pragma unroll 1
  for (int c = 0; c < 64; c++) {
    int cc = h * 64 + c;
    int gc = rB0 + cc;
    if (gc == grow) continue;
    float g = lds.c[r * 129 + cc];
    float d2 = fmaxf(sqr + (float)sq[gc] - 2.f * g, 0.f);
    u64 key = ((u64)__float_as_uint(d2) << 32) | (u32)gc;
    if (key < top[7]) {
      top[7] = key;
#pragma unroll
      for (int k = 7; k > 0; k--)
        if (top[k] < top[k - 1]) { u64 tmp = top[k]; top[k] = top[k - 1]; top[k - 1] = tmp; }
    }
  }
  u64* dst = part + ((size_t)grow * 64 + (size_t)(bj * 2 + h)) * 8;
#pragma unroll
  for (int k = 0; k < 8; k++) dst[k] = top[k];
}

// merge 512 partial candidates per row -> top-16 approx candidates
__global__ __launch_bounds__(256) void k_candmerge(const u64* __restrict__ part,
                                                   int* __restrict__ cand) {
  int row = blockIdx.x * 4 + (threadIdx.x >> 6);
  int l = threadIdx.x & 63;
  const u64* p = part + (size_t)row * 512 + (size_t)l * 8;
  u64 e[8];
#pragma unroll
  for (int k = 0; k < 8; k++) e[k] = p[k];
#pragma unroll 1
  for (int rnd = 0; rnd < 16; rnd++) {
    u64 m = e[0];
#pragma unroll
    for (int k = 1; k < 8; k++) m = e[k] < m ? e[k] : m;
#pragma unroll
    for (int off = 32; off; off >>= 1) {
      u64 o = __shfl_xor(m, off);
      m = o < m ? o : m;
    }
    if (l == 0) cand[row * 16 + rnd] = (int)(u32)m;
#pragma unroll
    for (int k = 0; k < 8; k++)
      if (e[k] == m) e[k] = ~0ull;
  }
}

// exact f64 re-rank of 16 candidates (+ noise tie-break) -> knn[row][7]
__global__ __launch_bounds__(256) void k_rerank(
    const float* __restrict__ feat, const double* __restrict__ A64,
    const double* __restrict__ C64, const double* __restrict__ sq,
    const float* __restrict__ noise, const int* __restrict__ cand,
    int* __restrict__ knn) {
  int row = blockIdx.x;
  int w = threadIdx.x >> 6, l = threadIdx.x & 63;
  __shared__ double xrow[Fn];
  __shared__ double dots[16];
  for (int e = threadIdx.x; e < Fn; e += 256)
    xrow[e] = fma((double)feat[(size_t)row * Fn + e], A64[e], C64[e]);
  __syncthreads();
  for (int m = w; m < 16; m += 4) {
    int c = cand[row * 16 + m];
    const float* fc = feat + (size_t)c * Fn;
    double s = 0.0;
    for (int e = l; e < Fn; e += 64) {
      double xj = fma((double)fc[e], A64[e], C64[e]);
      s = fma(xrow[e], xj, s);
    }
#pragma unroll
    for (int off = 32; off; off >>= 1) s += __shfl_xor(s, off);
    if (l == 0) dots[m] = s;
  }
  __syncthreads();
  if (threadIdx.x == 0) {
    double sr = sq[row];
    double bd[Kn]; int bi7[Kn];
#pragma unroll
    for (int k = 0; k < Kn; k++) { bd[k] = 1e300; bi7[k] = 0; }
#pragma unroll 1
    for (int m = 0; m < 16; m++) {
      int c = cand[row * 16 + m];
      double d2 = sr + sq[c] - 2.0 * dots[m];
      d2 = d2 > 0.0 ? d2 : 0.0;
      double d = sqrt(d2) + (double)noise[(size_t)row * Bn + c] * 1e-6;
      if (d < bd[Kn - 1]) {
        bd[Kn - 1] = d; bi7[Kn - 1] = c;
#pragma unroll
        for (int k = Kn - 1; k > 0; k--)
          if (bd[k] < bd[k - 1]) {
            double td = bd[k]; bd[k] = bd[k - 1]; bd[k - 1] = td;
            int ti = bi7[k]; bi7[k] = bi7[k - 1]; bi7[k - 1] = ti;
          }
      }
    }
#pragma unroll
    for (int k = 0; k < Kn; k++) knn[row * Kn + k] = bi7[k];
  }
}

// ---------- degree / dinv ----------
__global__ void k_deginit(float* __restrict__ deg) {
  int i = blockIdx.x * 256 + threadIdx.x;
  if (i < Bn) deg[i] = 1.f;
}
__global__ void k_degsc(const int* __restrict__ knn, float* __restrict__ deg) {
  int i = blockIdx.x * 256 + threadIdx.x;
  if (i < Bn * Kn) atomicAdd(&deg[knn[i]], 1.f);
}
__global__ void k_dinv(const float* __restrict__ deg, float* __restrict__ dinv) {
  int i = blockIdx.x * 256 + threadIdx.x;
  if (i < Bn) dinv[i] = rsqrtf(deg[i]);
}

// ---------- GCN aggregation ----------
__global__ void k_agginit(const float* __restrict__ h, const float* __restrict__ dinv,
                          const float* __restrict__ bias, float* __restrict__ out) {
  int t = blockIdx.x, f = threadIdx.x;
  float di = dinv[t];
  out[(size_t)t * Hn + f] = di * di * h[(size_t)t * Hn + f] + bias[f];
}
__global__ void k_aggsc(const float* __restrict__ h, const int* __restrict__ knn,
                        const float* __restrict__ dinv, float* __restrict__ out) {
  int s = blockIdx.x, f = threadIdx.x;
  float hv = h[(size_t)s * Hn + f] * dinv[s];
#pragma unroll
  for (int k = 0; k < Kn; k++) {
    int t = knn[s * Kn + k];
    atomicAdd(&out[(size_t)t * Hn + f], dinv[t] * hv);
  }
}

// BN (+relu) then hi/lo bf16 split for the next MFMA GEMM
__global__ void k_bnact_split(const float* __restrict__ x, const float* __restrict__ g,
                              const float* __restrict__ b, const float* __restrict__ m,
                              const float* __restrict__ v, int relu,
                              u16* __restrict__ oh, u16* __restrict__ ol) {
  int i = blockIdx.x * 256 + threadIdx.x;
  int c = i & (Hn - 1);
  float val = (x[i] - m[c]) * rsqrtf(v[c] + 1e-5f) * g[c] + b[c];
  if (relu) val = fmaxf(val, 0.f);
  __hip_bfloat16 h = __float2bfloat16(val);
  float hf = __bfloat162float(h);
  __hip_bfloat16 lo = __float2bfloat16(val - hf);
  oh[i] = *reinterpret_cast<u16*>(&h);
  ol[i] = *reinterpret_cast<u16*>(&lo);
}

// ---------- bf16-split MFMA GEMM: C[M×N] f32 = [A1|A2] @ W  (W given as Wt[N×K] hi/lo)
// 64x64 tile, BK=64, k-major LDS (64-row tiles -> 1024B per k-chunk).
// ep: 0 none, 1 +bias, 2 +bias+relu
__global__ __launch_bounds__(256) void k_mgemm(
    const u16* __restrict__ Ah1, const u16* __restrict__ Al1, int lda1,
    const u16* __restrict__ Ah2, const u16* __restrict__ Al2, int lda2, int Ksplit,
    const u16* __restrict__ Wth, const u16* __restrict__ Wtl,
    const float* __restrict__ bias, float* __restrict__ C, int N, int K, int ep) {
  __shared__ u16 tA[2][4096];   // [8 kq][64 row][16B], hi/lo
  __shared__ u16 tB[2][4096];
  const int tid = threadIdx.x;
  const int w = tid >> 6, l = tid & 63;
  const int m0 = blockIdx.y * 64, n0 = blockIdx.x * 64;
  const int fr = l & 15, fq = l >> 4;

  f32x4 acc[2][2];
  const f32x4 fz = {0.f, 0.f, 0.f, 0.f};
#pragma unroll
  for (int i = 0; i < 2; i++)
#pragma unroll
    for (int j = 0; j < 2; j++) acc[i][j] = fz;

  auto stage = [&](int k0) {
#pragma unroll
    for (int q = 0; q < 2; q++) {
      int s = w * 2 + q;            // kq 0..7
      int kg = k0 + s * 8;
      const u16* ah; const u16* al; int ld; int kk = kg;
      if (kg < Ksplit) { ah = Ah1; al = Al1; ld = lda1; }
      else             { ah = Ah2; al = Al2; ld = lda2; kk = kg - Ksplit; }
      gld16(ah + (size_t)(m0 + l) * ld + kk, (char*)&tA[0][0] + s * 1024);
      gld16(al + (size_t)(m0 + l) * ld + kk, (char*)&tA[1][0] + s * 1024);
      gld16(Wth + (size_t)(n0 + l) * K + kg, (char*)&tB[0][0] + s * 1024);
      gld16(Wtl + (size_t)(n0 + l) * K + kg, (char*)&tB[1][0] + s * 1024);
    }
  };

  stage(0);
  const int NT = K / GBK;
  for (int kt = 0; kt < NT; kt++) {
    __syncthreads();
#pragma unroll
    for (int kh = 0; kh < 2; kh++) {
      const int kb = (kh * 4 + fq) * 1024;   // FIX: 64 rows/tile -> 1024B per k-chunk
      short8 fa[2][2], fb[2][2];
#pragma unroll
      for (int i = 0; i < 2; i++) {
        int ar = (w >> 1) * 32 + i * 16 + fr;
        fa[0][i] = *reinterpret_cast<const short8*>((const char*)&tA[0][0] + kb + ar * 16);
        fa[1][i] = *reinterpret_cast<const short8*>((const char*)&tA[1][0] + kb + ar * 16);
        int br = (w & 1) * 32 + i * 16 + fr;
        fb[0][i] = *reinterpret_cast<const short8*>((const char*)&tB[0][0] + kb + br * 16);
        fb[1][i] = *reinterpret_cast<const short8*>((const char*)&tB[1][0] + kb + br * 16);
      }
#pragma unroll
      for (int i = 0; i < 2; i++)
#pragma unroll
        for (int j = 0; j < 2; j++) {
          acc[i][j] = __builtin_amdgcn_mfma_f32_16x16x32_bf16(fa[1][i], fb[0][j], acc[i][j], 0, 0, 0);
          acc[i][j] = __builtin_amdgcn_mfma_f32_16x16x32_bf16(fa[0][i], fb[1][j], acc[i][j], 0, 0, 0);
          acc[i][j] = __builtin_amdgcn_mfma_f32_16x16x32_bf16(fa[0][i], fb[0][j], acc[i][j], 0, 0, 0);
        }
    }
    __syncthreads();
    if (kt + 1 < NT) stage((kt + 1) * GBK);
  }

#pragma unroll
  for (int i = 0; i < 2; i++) {
    int rg0 = m0 + (w >> 1) * 32 + i * 16 + fq * 4;
#pragma unroll
    for (int j = 0; j < 2; j++) {
      int cg = n0 + (w & 1) * 32 + j * 16 + fr;
      float bv = (ep >= 1) ? bias[cg] : 0.f;
#pragma unroll
      for (int g = 0; g < 4; g++) {
        float val = acc[i][j][g] + bv;
        if (ep == 2) val = fmaxf(val, 0.f);
        C[(size_t)(rg0 + g) * N + cg] = val;
      }
    }
  }
}

// ---------- f32 GEMM (kept for tiny classifier2 only) ----------
__global__ __launch_bounds__(256) void k_gemm(
    const float* __restrict__ A1, int lda1,
    const float* __restrict__ Bw, const float* __restrict__ bias,
    float* __restrict__ C, int M, int N, int K, int ep) {
  __shared__ float As[16][65];
  __shared__ float Bs[16][64];
  int tid = threadIdx.x;
  int n0 = blockIdx.x * 64;
  int row0 = blockIdx.y * 64;
  int tx = tid & 15, ty = tid >> 4;
  float acc[4][4] = {};
  for (int k0 = 0; k0 < K; k0 += 16) {
    int kk = tid & 15, mi = tid >> 4;
#pragma unroll
    for (int p = 0; p < 4; p++) {
      int row = row0 + mi + p * 16;
      As[kk][mi + p * 16] = A1[(size_t)row * lda1 + k0 + kk];
    }
    int nj = tid & 63, kq = tid >> 6;
#pragma unroll
    for (int p = 0; p < 4; p++) {
      int kb = kq + p * 4;
      int n = n0 + nj;
      Bs[kb][nj] = (n < N) ? Bw[(size_t)(k0 + kb) * N + n] : 0.f;
    }
    __syncthreads();
#pragma unroll
    for (int kk2 = 0; kk2 < 16; kk2++) {
      float a[4], b[4];
#pragma unroll
      for (int i = 0; i < 4; i++) a[i] = As[kk2][ty * 4 + i];
#pragma unroll
      for (int j = 0; j < 4; j++) b[j] = Bs[kk2][tx * 4 + j];
#pragma unroll
      for (int i = 0; i < 4; i++)
#pragma unroll
        for (int j = 0; j < 4; j++) acc[i][j] += a[i] * b[j];
    }
    __syncthreads();
  }
#pragma unroll
  for (int i = 0; i < 4; i++) {
    int row = row0 + ty * 4 + i;
#pragma unroll
    for (int j = 0; j < 4; j++) {
      int n = n0 + tx * 4 + j;
      if (n < N) {
        float v = acc[i][j];
        if (ep >= 1) v += bias[n];
        if (ep == 2) v = fmaxf(v, 0.f);
        C[(size_t)row * N + n] = v;
      }
    }
  }
}

extern "C" void kernel_launch(void* const* d_in, const int* in_sizes, int n_in,
                              void* d_out, int out_size, void* d_ws, size_t ws_size,
                              hipStream_t stream) {
  const float* feat  = (const float*)d_in[0];
  const float* noise = (const float*)d_in[1];
  const float* bnf_g = (const float*)d_in[2];
  const float* bnf_b = (const float*)d_in[3];
  const float* bnf_m = (const float*)d_in[4];
  const float* bnf_v = (const float*)d_in[5];
  const float* W1 = (const float*)d_in[6];
  const float* b1 = (const float*)d_in[7];
  const float* W2 = (const float*)d_in[8];
  const float* b2 = (const float*)d_in[9];
  const float* W3 = (const float*)d_in[10];
  const float* b3 = (const float*)d_in[11];
  const float* bn1_g = (const float*)d_in[12];
  const float* bn1_b = (const float*)d_in[13];
  const float* bn1_m = (const float*)d_in[14];
  const float* bn1_v = (const float*)d_in[15];
  const float* bn2_g = (const float*)d_in[16];
  const float* bn2_b = (const float*)d_in[17];
  const float* bn2_m = (const float*)d_in[18];
  const float* bn2_v = (const float*)d_in[19];
  const float* bn3_g = (const float*)d_in[20];
  const float* bn3_b = (const float*)d_in[21];
  const float* bn3_m = (const float*)d_in[22];
  const float* bn3_v = (const float*)d_in[23];
  const float* Wc1 = (const float*)d_in[24];
  const float* bc1 = (const float*)d_in[25];
  const float* Wc2 = (const float*)d_in[26];
  const float* bc2 = (const float*)d_in[27];
  float* outp = (float*)d_out;

  char* w = (char*)d_ws;
  size_t off = 0;
  auto alloc = [&](size_t n) { void* p = w + off; off = (off + n + 255) & ~(size_t)255; return p; };
  u16*    Ahb  = (u16*)   alloc((size_t)Bn * Fn * 2);
  u16*    Alb  = (u16*)   alloc((size_t)Bn * Fn * 2);
  double* A64  = (double*)alloc(Fn * 8);
  double* C64  = (double*)alloc(Fn * 8);
  double* sq   = (double*)alloc(Bn * 8);
  u64*    part = (u64*)   alloc((size_t)Bn * 64 * 8 * 8);
  int*    cand = (int*)   alloc((size_t)Bn * 16 * 4);
  int*    knn  = (int*)   alloc((size_t)Bn * Kn * 4);
  float*  deg  = (float*) alloc(Bn * 4);
  float*  dinv = (float*) alloc(Bn * 4);
  float*  g1   = (float*) alloc((size_t)Bn * Hn * 4);
  float*  g2   = (float*) alloc((size_t)Bn * Hn * 4);
  float*  hid  = (float*) alloc((size_t)Bn * 128 * 4);
  u16*    sh   = (u16*)   alloc((size_t)Bn * Hn * 2);
  u16*    sl   = (u16*)   alloc((size_t)Bn * Hn * 2);
  u16*    W1th = (u16*)   alloc((size_t)Fn * Hn * 2);
  u16*    W1tl = (u16*)   alloc((size_t)Fn * Hn * 2);
  u16*    W2th = (u16*)   alloc((size_t)Hn * Hn * 2);
  u16*    W2tl = (u16*)   alloc((size_t)Hn * Hn * 2);
  u16*    W3th = (u16*)   alloc((size_t)Hn * Hn * 2);
  u16*    W3tl = (u16*)   alloc((size_t)Hn * Hn * 2);
  u16*    Wc1th= (u16*)   alloc((size_t)(Hn + Fn) * 128 * 2);
  u16*    Wc1tl= (u16*)   alloc((size_t)(Hn + Fn) * 128 * 2);
  (void)ws_size; (void)in_sizes; (void)n_in; (void)out_size;

  k_prep<<<(Fn + 255) / 256, 256, 0, stream>>>(bnf_g, bnf_b, bnf_m, bnf_v, A64, C64);
  k_bnsplit<<<(Bn * Fn) / 256, 256, 0, stream>>>(feat, A64, C64, Ahb, Alb);
  k_rowsq<<<Bn, 256, 0, stream>>>(feat, A64, C64, sq);
  k_wsplit<<<dim3(Hn / 32, Fn / 32), 256, 0, stream>>>(W1, Fn, Hn, W1th, W1tl);
  k_wsplit<<<dim3(Hn / 32, Hn / 32), 256, 0, stream>>>(W2, Hn, Hn, W2th, W2tl);
  k_wsplit<<<dim3(Hn / 32, Hn / 32), 256, 0, stream>>>(W3, Hn, Hn, W3th, W3tl);
  k_wsplit<<<dim3(128 / 32, (Hn + Fn) / 32), 256, 0, stream>>>(Wc1, Hn + Fn, 128, Wc1th, Wc1tl);

  k_gram<<<dim3(32, 32), 256, 0, stream>>>(Ahb, Alb, sq, part);
  k_candmerge<<<Bn / 4, 256, 0, stream>>>(part, cand);
  k_rerank<<<Bn, 256, 0, stream>>>(feat, A64, C64, sq, noise, cand, knn);
  k_deginit<<<(Bn + 255) / 256, 256, 0, stream>>>(deg);
  k_degsc<<<(Bn * Kn + 255) / 256, 256, 0, stream>>>(knn, deg);
  k_dinv<<<(Bn + 255) / 256, 256, 0, stream>>>(deg, dinv);

  dim3 gm(Hn / 64, Bn / 64);
  // layer 1
  k_mgemm<<<gm, 256, 0, stream>>>(Ahb, Alb, Fn, Ahb, Alb, Fn, Fn, W1th, W1tl, nullptr, g1, Hn, Fn, 0);
  k_agginit<<<Bn, Hn, 0, stream>>>(g1, dinv, b1, g2);
  k_aggsc<<<Bn, Hn, 0, stream>>>(g1, knn, dinv, g2);
  k_bnact_split<<<(Bn * Hn) / 256, 256, 0, stream>>>(g2, bn1_g, bn1_b, bn1_m, bn1_v, 1, sh, sl);
  // layer 2
  k_mgemm<<<gm, 256, 0, stream>>>(sh, sl, Hn, sh, sl, Hn, Hn, W2th, W2tl, nullptr, g1, Hn, Hn, 0);
  k_agginit<<<Bn, Hn, 0, stream>>>(g1, dinv, b2, g2);
  k_aggsc<<<Bn, Hn, 0, stream>>>(g1, knn, dinv, g2);
  k_bnact_split<<<(Bn * Hn) / 256, 256, 0, stream>>>(g2, bn2_g, bn2_b, bn2_m, bn2_v, 1, sh, sl);
  // layer 3
  k_mgemm<<<gm, 256, 0, stream>>>(sh, sl, Hn, sh, sl, Hn, Hn, W3th, W3tl, nullptr, g1, Hn, Hn, 0);
  k_agginit<<<Bn, Hn, 0, stream>>>(g1, dinv, b3, g2);
  k_aggsc<<<Bn, Hn, 0, stream>>>(g1, knn, dinv, g2);
  k_bnact_split<<<(Bn * Hn) / 256, 256, 0, stream>>>(g2, bn3_g, bn3_b, bn3_m, bn3_v, 0, sh, sl);
  // classifier1: comb = [h3 | x] in bf16 splits
  k_mgemm<<<dim3(128 / 64, Bn / 64), 256, 0, stream>>>(sh, sl, Hn, Ahb, Alb, Fn, Hn,
                                                       Wc1th, Wc1tl, bc1, hid, 128, Hn + Fn, 2);
  // classifier2 (tiny, f32)
  k_gemm<<<dim3(1, Bn / 64), 256, 0, stream>>>(hid, 128, Wc2, bc2, outp, Bn, Cn, 128, 1);
}

// Round 5
// 648.358 us; speedup vs baseline: 4.5170x; 1.1796x over previous
//
#include <hip/hip_runtime.h>
#include <hip/hip_bf16.h>
#include <math.h>

#define Bn 4096
#define Fn 1536
#define Hn 256
#define Cn 38
#define Kn 7
#define GBK 64

typedef __attribute__((ext_vector_type(8))) short short8;
typedef __attribute__((ext_vector_type(4))) float f32x4;
typedef unsigned long long u64;
typedef unsigned int u32;
typedef unsigned short u16;

__device__ __forceinline__ void gld16(const void* g, void* l) {
  __builtin_amdgcn_global_load_lds((const __attribute__((address_space(1))) unsigned int*)g,
                                   (__attribute__((address_space(3))) unsigned int*)l, 16, 0, 0);
}

// ---------- BN param prep (f64): x = feat*A + C ----------
__global__ void k_prep(const float* __restrict__ g, const float* __restrict__ b,
                       const float* __restrict__ m, const float* __restrict__ v,
                       double* __restrict__ A64, double* __restrict__ C64) {
  int f = blockIdx.x * 256 + threadIdx.x;
  if (f < Fn) {
    double rs = 1.0 / sqrt((double)v[f] + 1e-5);
    double a = (double)g[f] * rs;
    A64[f] = a;
    C64[f] = (double)b[f] - (double)m[f] * a;
  }
}

// Ah/Al = bf16 hi/lo split of BN(features)  (2-D grid: no 64-bit mod)
__global__ void k_bnsplit(const float* __restrict__ feat, const double* __restrict__ A64,
                          const double* __restrict__ C64,
                          u16* __restrict__ Ah, u16* __restrict__ Al) {
  int f = blockIdx.x * 256 + threadIdx.x;
  size_t i = (size_t)blockIdx.y * Fn + f;
  float x = (float)fma((double)feat[i], A64[f], C64[f]);
  __hip_bfloat16 h = __float2bfloat16(x);
  float hf = __bfloat162float(h);
  __hip_bfloat16 lo = __float2bfloat16(x - hf);
  Ah[i] = *reinterpret_cast<u16*>(&h);
  Al[i] = *reinterpret_cast<u16*>(&lo);
}

// sq[i] = sum_f x64[i][f]^2  (f64)
__global__ void k_rowsq(const float* __restrict__ feat, const double* __restrict__ A64,
                        const double* __restrict__ C64, double* __restrict__ sq) {
  int row = blockIdx.x, tid = threadIdx.x;
  const float* fr = feat + (size_t)row * Fn;
  double s = 0.0;
  for (int f = tid; f < Fn; f += 256) {
    double x = fma((double)fr[f], A64[f], C64[f]);
    s += x * x;
  }
  for (int o = 32; o > 0; o >>= 1) s += __shfl_down(s, o);
  __shared__ double red[4];
  if ((tid & 63) == 0) red[tid >> 6] = s;
  __syncthreads();
  if (tid == 0) sq[row] = red[0] + red[1] + red[2] + red[3];
}

// transpose + hi/lo split weights: W[K×N] f32 -> Wt[N×K] bf16 hi/lo
__global__ void k_wsplit(const float* __restrict__ W, int K, int N,
                         u16* __restrict__ Wth, u16* __restrict__ Wtl) {
  __shared__ float t[32][33];
  int k0 = blockIdx.y * 32, n0 = blockIdx.x * 32;
  int tx = threadIdx.x & 31, ty = threadIdx.x >> 5;  // ty 0..7
  for (int p = 0; p < 32; p += 8) {
    int k = k0 + ty + p, n = n0 + tx;
    t[ty + p][tx] = (k < K && n < N) ? W[(size_t)k * N + n] : 0.f;
  }
  __syncthreads();
  for (int p = 0; p < 32; p += 8) {
    int n = n0 + ty + p, k = k0 + tx;
    if (n < N && k < K) {
      float x = t[tx][ty + p];
      __hip_bfloat16 h = __float2bfloat16(x);
      float hf = __bfloat162float(h);
      __hip_bfloat16 lo = __float2bfloat16(x - hf);
      Wth[(size_t)n * K + k] = *reinterpret_cast<u16*>(&h);
      Wtl[(size_t)n * K + k] = *reinterpret_cast<u16*>(&lo);
    }
  }
}

// ---------- single-bf16 MFMA Gram (search only) + fused per-row/64-col top-8 ----------
// LDS per matrix: [2 kh][128 rows][64 B], m201 st_16x32 swizzle:
//   stored[row][cB] = global[row][cB ^ ((row&8)?32:0)], read colB = ((l>>4)*16) ^ ((row&8)?32:0)
__global__ __launch_bounds__(256) void k_gram(
    const u16* __restrict__ Ah, const double* __restrict__ sq, u64* __restrict__ part) {
  __shared__ union {
    u16 t[2][8192];        // A,B tiles: [kh*4096 + row*32 + col], 16 KB each
    float c[128 * 129];    // C tile (epilogue)
  } lds;
  const int tid = threadIdx.x;
  const int w = tid >> 6, l = tid & 63;
  const int bi = blockIdx.y, bj = blockIdx.x;
  const int rA0 = bi * 128, rB0 = bj * 128;

  f32x4 acc[4][4];
  const f32x4 fz = {0.f, 0.f, 0.f, 0.f};
#pragma unroll
  for (int i = 0; i < 4; i++)
#pragma unroll
    for (int j = 0; j < 4; j++) acc[i][j] = fz;

  // staging: 32 segs of 1024 B (2 matrices × 2 kh × 8 segs); seg covers 16 rows × 64 B
  auto stage = [&](int k0) {
#pragma unroll
    for (int q = 0; q < 8; q++) {
      int idx = w * 8 + q;
      int mm = idx >> 4, kh = (idx >> 3) & 1, s = idx & 7;
      int row = s * 16 + (l >> 2);
      int colel = ((l & 3) * 8) ^ ((row & 8) ? 16 : 0);   // inverse-swizzled global source
      int r0 = mm ? rB0 : rA0;
      gld16(Ah + (size_t)(r0 + row) * Fn + k0 + kh * 32 + colel,
            (char*)&lds.t[mm][0] + kh * 8192 + s * 1024);  // linear dest, +lane*16 by HW
    }
  };

  const int swz = (l & 8) ? 32 : 0;
  const int cB = ((l >> 4) * 16) ^ swz;

  stage(0);
  const int NT = Fn / GBK;
  for (int kt = 0; kt < NT; kt++) {
    __syncthreads();
#pragma unroll
    for (int kh = 0; kh < 2; kh++) {
      short8 fa[4], fb[4];
#pragma unroll
      for (int i = 0; i < 4; i++) {
        int ar = (w >> 1) * 64 + i * 16 + (l & 15);
        fa[i] = *reinterpret_cast<const short8*>((const char*)&lds.t[0][0] + kh * 8192 + ar * 64 + cB);
        int br = (w & 1) * 64 + i * 16 + (l & 15);
        fb[i] = *reinterpret_cast<const short8*>((const char*)&lds.t[1][0] + kh * 8192 + br * 64 + cB);
      }
#pragma unroll
      for (int i = 0; i < 4; i++)
#pragma unroll
        for (int j = 0; j < 4; j++)
          acc[i][j] = __builtin_amdgcn_mfma_f32_16x16x32_bf16(fa[i], fb[j], acc[i][j], 0, 0, 0);
    }
    __syncthreads();
    if (kt + 1 < NT) stage((kt + 1) * GBK);
  }

  // epilogue: C tile to LDS
  const int fr = l & 15, fq = l >> 4;
#pragma unroll
  for (int i = 0; i < 4; i++) {
    int r0 = (w >> 1) * 64 + i * 16 + fq * 4;
#pragma unroll
    for (int j = 0; j < 4; j++) {
      int c0 = (w & 1) * 64 + j * 16 + fr;
#pragma unroll
      for (int g = 0; g < 4; g++)
        lds.c[(r0 + g) * 129 + c0] = acc[i][j][g];
    }
  }
  __syncthreads();

  // selection: 2 threads per row, each scans 64 cols -> top-8 packed (d2bits<<32 | idx)
  int r = tid >> 1, h = tid & 1;
  int grow = rA0 + r;
  float sqr = (float)sq[grow];
  u64 top[8];
#pragma unroll
  for (int k = 0; k < 8; k++) top[k] = ~0ull;
#pragma unroll 1
  for (int c = 0; c < 64; c++) {
    int cc = h * 64 + c;
    int gc = rB0 + cc;
    if (gc == grow) continue;
    float g = lds.c[r * 129 + cc];
    float d2 = fmaxf(sqr + (float)sq[gc] - 2.f * g, 0.f);
    u64 key = ((u64)__float_as_uint(d2) << 32) | (u32)gc;
    if (key < top[7]) {
      top[7] = key;
#pragma unroll
      for (int k = 7; k > 0; k--)
        if (top[k] < top[k - 1]) { u64 tmp = top[k]; top[k] = top[k - 1]; top[k - 1] = tmp; }
    }
  }
  u64* dst = part + ((size_t)grow * 64 + (size_t)(bj * 2 + h)) * 8;
#pragma unroll
  for (int k = 0; k < 8; k++) dst[k] = top[k];
}

// merge 512 partial candidates per row -> top-16 approx candidates
__global__ __launch_bounds__(256) void k_candmerge(const u64* __restrict__ part,
                                                   int* __restrict__ cand) {
  int row = blockIdx.x * 4 + (threadIdx.x >> 6);
  int l = threadIdx.x & 63;
  const u64* p = part + (size_t)row * 512 + (size_t)l * 8;
  u64 e[8];
#pragma unroll
  for (int k = 0; k < 8; k++) e[k] = p[k];
#pragma unroll 1
  for (int rnd = 0; rnd < 16; rnd++) {
    u64 m = e[0];
#pragma unroll
    for (int k = 1; k < 8; k++) m = e[k] < m ? e[k] : m;
#pragma unroll
    for (int off = 32; off; off >>= 1) {
      u64 o = __shfl_xor(m, off);
      m = o < m ? o : m;
    }
    if (l == 0) cand[row * 16 + rnd] = (int)(u32)m;
#pragma unroll
    for (int k = 0; k < 8; k++)
      if (e[k] == m) e[k] = ~0ull;
  }
}

// exact f64 re-rank of 16 candidates (+ noise tie-break) -> knn[row][7]
__global__ __launch_bounds__(256) void k_rerank(
    const float* __restrict__ feat, const double* __restrict__ A64,
    const double* __restrict__ C64, const double* __restrict__ sq,
    const float* __restrict__ noise, const int* __restrict__ cand,
    int* __restrict__ knn) {
  int row = blockIdx.x;
  int w = threadIdx.x >> 6, l = threadIdx.x & 63;
  __shared__ double xrow[Fn];
  __shared__ double dots[16];
  for (int e = threadIdx.x; e < Fn; e += 256)
    xrow[e] = fma((double)feat[(size_t)row * Fn + e], A64[e], C64[e]);
  __syncthreads();
  for (int m = w; m < 16; m += 4) {
    int c = cand[row * 16 + m];
    const float* fc = feat + (size_t)c * Fn;
    double s = 0.0;
    for (int e = l; e < Fn; e += 64) {
      double xj = fma((double)fc[e], A64[e], C64[e]);
      s = fma(xrow[e], xj, s);
    }
#pragma unroll
    for (int off = 32; off; off >>= 1) s += __shfl_xor(s, off);
    if (l == 0) dots[m] = s;
  }
  __syncthreads();
  if (threadIdx.x == 0) {
    double sr = sq[row];
    double bd[Kn]; int bi7[Kn];
#pragma unroll
    for (int k = 0; k < Kn; k++) { bd[k] = 1e300; bi7[k] = 0; }
#pragma unroll 1
    for (int m = 0; m < 16; m++) {
      int c = cand[row * 16 + m];
      double d2 = sr + sq[c] - 2.0 * dots[m];
      d2 = d2 > 0.0 ? d2 : 0.0;
      double d = sqrt(d2) + (double)noise[(size_t)row * Bn + c] * 1e-6;
      if (d < bd[Kn - 1]) {
        bd[Kn - 1] = d; bi7[Kn - 1] = c;
#pragma unroll
        for (int k = Kn - 1; k > 0; k--)
          if (bd[k] < bd[k - 1]) {
            double td = bd[k]; bd[k] = bd[k - 1]; bd[k - 1] = td;
            int ti = bi7[k]; bi7[k] = bi7[k - 1]; bi7[k - 1] = ti;
          }
      }
    }
#pragma unroll
    for (int k = 0; k < Kn; k++) knn[row * Kn + k] = bi7[k];
  }
}

// ---------- degree / dinv ----------
__global__ void k_deginit(float* __restrict__ deg) {
  int i = blockIdx.x * 256 + threadIdx.x;
  if (i < Bn) deg[i] = 1.f;
}
__global__ void k_degsc(const int* __restrict__ knn, float* __restrict__ deg) {
  int i = blockIdx.x * 256 + threadIdx.x;
  if (i < Bn * Kn) atomicAdd(&deg[knn[i]], 1.f);
}
__global__ void k_dinv(const float* __restrict__ deg, float* __restrict__ dinv) {
  int i = blockIdx.x * 256 + threadIdx.x;
  if (i < Bn) dinv[i] = rsqrtf(deg[i]);
}

// ---------- GCN aggregation ----------
__global__ void k_agginit(const float* __restrict__ h, const float* __restrict__ dinv,
                          const float* __restrict__ bias, float* __restrict__ out) {
  int t = blockIdx.x, f = threadIdx.x;
  float di = dinv[t];
  out[(size_t)t * Hn + f] = di * di * h[(size_t)t * Hn + f] + bias[f];
}
__global__ void k_aggsc(const float* __restrict__ h, const int* __restrict__ knn,
                        const float* __restrict__ dinv, float* __restrict__ out) {
  int s = blockIdx.x, f = threadIdx.x;
  float hv = h[(size_t)s * Hn + f] * dinv[s];
#pragma unroll
  for (int k = 0; k < Kn; k++) {
    int t = knn[s * Kn + k];
    atomicAdd(&out[(size_t)t * Hn + f], dinv[t] * hv);
  }
}

// BN (+relu) then hi/lo bf16 split for the next MFMA GEMM
__global__ void k_bnact_split(const float* __restrict__ x, const float* __restrict__ g,
                              const float* __restrict__ b, const float* __restrict__ m,
                              const float* __restrict__ v, int relu,
                              u16* __restrict__ oh, u16* __restrict__ ol) {
  int i = blockIdx.x * 256 + threadIdx.x;
  int c = i & (Hn - 1);
  float val = (x[i] - m[c]) * rsqrtf(v[c] + 1e-5f) * g[c] + b[c];
  if (relu) val = fmaxf(val, 0.f);
  __hip_bfloat16 h = __float2bfloat16(val);
  float hf = __bfloat162float(h);
  __hip_bfloat16 lo = __float2bfloat16(val - hf);
  oh[i] = *reinterpret_cast<u16*>(&h);
  ol[i] = *reinterpret_cast<u16*>(&lo);
}

// ---------- bf16-split MFMA GEMM: C[M×N] f32 = [A1|A2] @ W  (W given as Wt[N×K] hi/lo)
// 64x64 tile, BK=64, k-major LDS (64-row tiles -> 1024B per k-chunk).
// ep: 0 none, 1 +bias, 2 +bias+relu
__global__ __launch_bounds__(256) void k_mgemm(
    const u16* __restrict__ Ah1, const u16* __restrict__ Al1, int lda1,
    const u16* __restrict__ Ah2, const u16* __restrict__ Al2, int lda2, int Ksplit,
    const u16* __restrict__ Wth, const u16* __restrict__ Wtl,
    const float* __restrict__ bias, float* __restrict__ C, int N, int K, int ep) {
  __shared__ u16 tA[2][4096];   // [8 kq][64 row][16B], hi/lo
  __shared__ u16 tB[2][4096];
  const int tid = threadIdx.x;
  const int w = tid >> 6, l = tid & 63;
  const int m0 = blockIdx.y * 64, n0 = blockIdx.x * 64;
  const int fr = l & 15, fq = l >> 4;

  f32x4 acc[2][2];
  const f32x4 fz = {0.f, 0.f, 0.f, 0.f};
#pragma unroll
  for (int i = 0; i < 2; i++)
#pragma unroll
    for (int j = 0; j < 2; j++) acc[i][j] = fz;

  auto stage = [&](int k0) {
#pragma unroll
    for (int q = 0; q < 2; q++) {
      int s = w * 2 + q;            // kq 0..7
      int kg = k0 + s * 8;
      const u16* ah; const u16* al; int ld; int kk = kg;
      if (kg < Ksplit) { ah = Ah1; al = Al1; ld = lda1; }
      else             { ah = Ah2; al = Al2; ld = lda2; kk = kg - Ksplit; }
      gld16(ah + (size_t)(m0 + l) * ld + kk, (char*)&tA[0][0] + s * 1024);
      gld16(al + (size_t)(m0 + l) * ld + kk, (char*)&tA[1][0] + s * 1024);
      gld16(Wth + (size_t)(n0 + l) * K + kg, (char*)&tB[0][0] + s * 1024);
      gld16(Wtl + (size_t)(n0 + l) * K + kg, (char*)&tB[1][0] + s * 1024);
    }
  };

  stage(0);
  const int NT = K / GBK;
  for (int kt = 0; kt < NT; kt++) {
    __syncthreads();
#pragma unroll
    for (int kh = 0; kh < 2; kh++) {
      const int kb = (kh * 4 + fq) * 1024;   // 64 rows/tile -> 1024B per k-chunk
      short8 fa[2][2], fb[2][2];
#pragma unroll
      for (int i = 0; i < 2; i++) {
        int ar = (w >> 1) * 32 + i * 16 + fr;
        fa[0][i] = *reinterpret_cast<const short8*>((const char*)&tA[0][0] + kb + ar * 16);
        fa[1][i] = *reinterpret_cast<const short8*>((const char*)&tA[1][0] + kb + ar * 16);
        int br = (w & 1) * 32 + i * 16 + fr;
        fb[0][i] = *reinterpret_cast<const short8*>((const char*)&tB[0][0] + kb + br * 16);
        fb[1][i] = *reinterpret_cast<const short8*>((const char*)&tB[1][0] + kb + br * 16);
      }
#pragma unroll
      for (int i = 0; i < 2; i++)
#pragma unroll
        for (int j = 0; j < 2; j++) {
          acc[i][j] = __builtin_amdgcn_mfma_f32_16x16x32_bf16(fa[1][i], fb[0][j], acc[i][j], 0, 0, 0);
          acc[i][j] = __builtin_amdgcn_mfma_f32_16x16x32_bf16(fa[0][i], fb[1][j], acc[i][j], 0, 0, 0);
          acc[i][j] = __builtin_amdgcn_mfma_f32_16x16x32_bf16(fa[0][i], fb[0][j], acc[i][j], 0, 0, 0);
        }
    }
    __syncthreads();
    if (kt + 1 < NT) stage((kt + 1) * GBK);
  }

#pragma unroll
  for (int i = 0; i < 2; i++) {
    int rg0 = m0 + (w >> 1) * 32 + i * 16 + fq * 4;
#pragma unroll
    for (int j = 0; j < 2; j++) {
      int cg = n0 + (w & 1) * 32 + j * 16 + fr;
      float bv = (ep >= 1) ? bias[cg] : 0.f;
#pragma unroll
      for (int g = 0; g < 4; g++) {
        float val = acc[i][j][g] + bv;
        if (ep == 2) val = fmaxf(val, 0.f);
        C[(size_t)(rg0 + g) * N + cg] = val;
      }
    }
  }
}

// ---------- f32 GEMM (kept for tiny classifier2 only) ----------
__global__ __launch_bounds__(256) void k_gemm(
    const float* __restrict__ A1, int lda1,
    const float* __restrict__ Bw, const float* __restrict__ bias,
    float* __restrict__ C, int M, int N, int K, int ep) {
  __shared__ float As[16][65];
  __shared__ float Bs[16][64];
  int tid = threadIdx.x;
  int n0 = blockIdx.x * 64;
  int row0 = blockIdx.y * 64;
  int tx = tid & 15, ty = tid >> 4;
  float acc[4][4] = {};
  for (int k0 = 0; k0 < K; k0 += 16) {
    int kk = tid & 15, mi = tid >> 4;
#pragma unroll
    for (int p = 0; p < 4; p++) {
      int row = row0 + mi + p * 16;
      As[kk][mi + p * 16] = A1[(size_t)row * lda1 + k0 + kk];
    }
    int nj = tid & 63, kq = tid >> 6;
#pragma unroll
    for (int p = 0; p < 4; p++) {
      int kb = kq + p * 4;
      int n = n0 + nj;
      Bs[kb][nj] = (n < N) ? Bw[(size_t)(k0 + kb) * N + n] : 0.f;
    }
    __syncthreads();
#pragma unroll
    for (int kk2 = 0; kk2 < 16; kk2++) {
      float a[4], b[4];
#pragma unroll
      for (int i = 0; i < 4; i++) a[i] = As[kk2][ty * 4 + i];
#pragma unroll
      for (int j = 0; j < 4; j++) b[j] = Bs[kk2][tx * 4 + j];
#pragma unroll
      for (int i = 0; i < 4; i++)
#pragma unroll
        for (int j = 0; j < 4; j++) acc[i][j] += a[i] * b[j];
    }
    __syncthreads();
  }
#pragma unroll
  for (int i = 0; i < 4; i++) {
    int row = row0 + ty * 4 + i;
#pragma unroll
    for (int j = 0; j < 4; j++) {
      int n = n0 + tx * 4 + j;
      if (n < N) {
        float v = acc[i][j];
        if (ep >= 1) v += bias[n];
        if (ep == 2) v = fmaxf(v, 0.f);
        C[(size_t)row * N + n] = v;
      }
    }
  }
}

extern "C" void kernel_launch(void* const* d_in, const int* in_sizes, int n_in,
                              void* d_out, int out_size, void* d_ws, size_t ws_size,
                              hipStream_t stream) {
  const float* feat  = (const float*)d_in[0];
  const float* noise = (const float*)d_in[1];
  const float* bnf_g = (const float*)d_in[2];
  const float* bnf_b = (const float*)d_in[3];
  const float* bnf_m = (const float*)d_in[4];
  const float* bnf_v = (const float*)d_in[5];
  const float* W1 = (const float*)d_in[6];
  const float* b1 = (const float*)d_in[7];
  const float* W2 = (const float*)d_in[8];
  const float* b2 = (const float*)d_in[9];
  const float* W3 = (const float*)d_in[10];
  const float* b3 = (const float*)d_in[11];
  const float* bn1_g = (const float*)d_in[12];
  const float* bn1_b = (const float*)d_in[13];
  const float* bn1_m = (const float*)d_in[14];
  const float* bn1_v = (const float*)d_in[15];
  const float* bn2_g = (const float*)d_in[16];
  const float* bn2_b = (const float*)d_in[17];
  const float* bn2_m = (const float*)d_in[18];
  const float* bn2_v = (const float*)d_in[19];
  const float* bn3_g = (const float*)d_in[20];
  const float* bn3_b = (const float*)d_in[21];
  const float* bn3_m = (const float*)d_in[22];
  const float* bn3_v = (const float*)d_in[23];
  const float* Wc1 = (const float*)d_in[24];
  const float* bc1 = (const float*)d_in[25];
  const float* Wc2 = (const float*)d_in[26];
  const float* bc2 = (const float*)d_in[27];
  float* outp = (float*)d_out;

  char* w = (char*)d_ws;
  size_t off = 0;
  auto alloc = [&](size_t n) { void* p = w + off; off = (off + n + 255) & ~(size_t)255; return p; };
  u16*    Ahb  = (u16*)   alloc((size_t)Bn * Fn * 2);
  u16*    Alb  = (u16*)   alloc((size_t)Bn * Fn * 2);
  double* A64  = (double*)alloc(Fn * 8);
  double* C64  = (double*)alloc(Fn * 8);
  double* sq   = (double*)alloc(Bn * 8);
  u64*    part = (u64*)   alloc((size_t)Bn * 64 * 8 * 8);
  int*    cand = (int*)   alloc((size_t)Bn * 16 * 4);
  int*    knn  = (int*)   alloc((size_t)Bn * Kn * 4);
  float*  deg  = (float*) alloc(Bn * 4);
  float*  dinv = (float*) alloc(Bn * 4);
  float*  g1   = (float*) alloc((size_t)Bn * Hn * 4);
  float*  g2   = (float*) alloc((size_t)Bn * Hn * 4);
  float*  hid  = (float*) alloc((size_t)Bn * 128 * 4);
  u16*    sh   = (u16*)   alloc((size_t)Bn * Hn * 2);
  u16*    sl   = (u16*)   alloc((size_t)Bn * Hn * 2);
  u16*    W1th = (u16*)   alloc((size_t)Fn * Hn * 2);
  u16*    W1tl = (u16*)   alloc((size_t)Fn * Hn * 2);
  u16*    W2th = (u16*)   alloc((size_t)Hn * Hn * 2);
  u16*    W2tl = (u16*)   alloc((size_t)Hn * Hn * 2);
  u16*    W3th = (u16*)   alloc((size_t)Hn * Hn * 2);
  u16*    W3tl = (u16*)   alloc((size_t)Hn * Hn * 2);
  u16*    Wc1th= (u16*)   alloc((size_t)(Hn + Fn) * 128 * 2);
  u16*    Wc1tl= (u16*)   alloc((size_t)(Hn + Fn) * 128 * 2);
  (void)ws_size; (void)in_sizes; (void)n_in; (void)out_size;

  k_prep<<<(Fn + 255) / 256, 256, 0, stream>>>(bnf_g, bnf_b, bnf_m, bnf_v, A64, C64);
  k_bnsplit<<<dim3(Fn / 256, Bn), 256, 0, stream>>>(feat, A64, C64, Ahb, Alb);
  k_rowsq<<<Bn, 256, 0, stream>>>(feat, A64, C64, sq);
  k_wsplit<<<dim3(Hn / 32, Fn / 32), 256, 0, stream>>>(W1, Fn, Hn, W1th, W1tl);
  k_wsplit<<<dim3(Hn / 32, Hn / 32), 256, 0, stream>>>(W2, Hn, Hn, W2th, W2tl);
  k_wsplit<<<dim3(Hn / 32, Hn / 32), 256, 0, stream>>>(W3, Hn, Hn, W3th, W3tl);
  k_wsplit<<<dim3(128 / 32, (Hn + Fn) / 32), 256, 0, stream>>>(Wc1, Hn + Fn, 128, Wc1th, Wc1tl);

  k_gram<<<dim3(32, 32), 256, 0, stream>>>(Ahb, sq, part);
  k_candmerge<<<Bn / 4, 256, 0, stream>>>(part, cand);
  k_rerank<<<Bn, 256, 0, stream>>>(feat, A64, C64, sq, noise, cand, knn);
  k_deginit<<<(Bn + 255) / 256, 256, 0, stream>>>(deg);
  k_degsc<<<(Bn * Kn + 255) / 256, 256, 0, stream>>>(knn, deg);
  k_dinv<<<(Bn + 255) / 256, 256, 0, stream>>>(deg, dinv);

  dim3 gm(Hn / 64, Bn / 64);
  // layer 1
  k_mgemm<<<gm, 256, 0, stream>>>(Ahb, Alb, Fn, Ahb, Alb, Fn, Fn, W1th, W1tl, nullptr, g1, Hn, Fn, 0);
  k_agginit<<<Bn, Hn, 0, stream>>>(g1, dinv, b1, g2);
  k_aggsc<<<Bn, Hn, 0, stream>>>(g1, knn, dinv, g2);
  k_bnact_split<<<(Bn * Hn) / 256, 256, 0, stream>>>(g2, bn1_g, bn1_b, bn1_m, bn1_v, 1, sh, sl);
  // layer 2
  k_mgemm<<<gm, 256, 0, stream>>>(sh, sl, Hn, sh, sl, Hn, Hn, W2th, W2tl, nullptr, g1, Hn, Hn, 0);
  k_agginit<<<Bn, Hn, 0, stream>>>(g1, dinv, b2, g2);
  k_aggsc<<<Bn, Hn, 0, stream>>>(g1, knn, dinv, g2);
  k_bnact_split<<<(Bn * Hn) / 256, 256, 0, stream>>>(g2, bn2_g, bn2_b, bn2_m, bn2_v, 1, sh, sl);
  // layer 3
  k_mgemm<<<gm, 256, 0, stream>>>(sh, sl, Hn, sh, sl, Hn, Hn, W3th, W3tl, nullptr, g1, Hn, Hn, 0);
  k_agginit<<<Bn, Hn, 0, stream>>>(g1, dinv, b3, g2);
  k_aggsc<<<Bn, Hn, 0, stream>>>(g1, knn, dinv, g2);
  k_bnact_split<<<(Bn * Hn) / 256, 256, 0, stream>>>(g2, bn3_g, bn3_b, bn3_m, bn3_v, 0, sh, sl);
  // classifier1: comb = [h3 | x] in bf16 splits
  k_mgemm<<<dim3(128 / 64, Bn / 64), 256, 0, stream>>>(sh, sl, Hn, Ahb, Alb, Fn, Hn,
                                                       Wc1th, Wc1tl, bc1, hid, 128, Hn + Fn, 2);
  // classifier2 (tiny, f32)
  k_gemm<<<dim3(1, Bn / 64), 256, 0, stream>>>(hid, 128, Wc2, bc2, outp, Bn, Cn, 128, 1);
}

// Round 6
// 586.628 us; speedup vs baseline: 4.9923x; 1.1052x over previous
//
#include <hip/hip_runtime.h>
#include <hip/hip_bf16.h>
#include <math.h>

#define Bn 4096
#define Fn 1536
#define Hn 256
#define Cn 38
#define Kn 7
#define GBK 64

typedef __attribute__((ext_vector_type(8))) short short8;
typedef __attribute__((ext_vector_type(4))) float f32x4;
typedef unsigned long long u64;
typedef unsigned int u32;
typedef unsigned short u16;

__device__ __forceinline__ void gld16(const void* g, void* l) {
  __builtin_amdgcn_global_load_lds((const __attribute__((address_space(1))) unsigned int*)g,
                                   (__attribute__((address_space(3))) unsigned int*)l, 16, 0, 0);
}

// ---------- BN param prep (f64): x = feat*A + C ----------
__global__ void k_prep(const float* __restrict__ g, const float* __restrict__ b,
                       const float* __restrict__ m, const float* __restrict__ v,
                       double* __restrict__ A64, double* __restrict__ C64) {
  int f = blockIdx.x * 256 + threadIdx.x;
  if (f < Fn) {
    double rs = 1.0 / sqrt((double)v[f] + 1e-5);
    double a = (double)g[f] * rs;
    A64[f] = a;
    C64[f] = (double)b[f] - (double)m[f] * a;
  }
}

// Ah/Al = bf16 hi/lo split of BN(features); one row per block, 8 elems/thread
__global__ void k_bnsplit(const float* __restrict__ feat, const double* __restrict__ A64,
                          const double* __restrict__ C64,
                          u16* __restrict__ Ah, u16* __restrict__ Al) {
  int row = blockIdx.x;
  int f0 = threadIdx.x * 8;
  const float* fr = feat + (size_t)row * Fn + f0;
  float4 a = *reinterpret_cast<const float4*>(fr);
  float4 b = *reinterpret_cast<const float4*>(fr + 4);
  float xs[8] = {a.x, a.y, a.z, a.w, b.x, b.y, b.z, b.w};
  short8 hv, lv;
#pragma unroll
  for (int k = 0; k < 8; k++) {
    float x = (float)fma((double)xs[k], A64[f0 + k], C64[f0 + k]);
    __hip_bfloat16 h = __float2bfloat16(x);
    float hf = __bfloat162float(h);
    __hip_bfloat16 lo = __float2bfloat16(x - hf);
    hv[k] = (short)*reinterpret_cast<u16*>(&h);
    lv[k] = (short)*reinterpret_cast<u16*>(&lo);
  }
  *reinterpret_cast<short8*>(Ah + (size_t)row * Fn + f0) = hv;
  *reinterpret_cast<short8*>(Al + (size_t)row * Fn + f0) = lv;
}

// sq[i] = sum_f x64[i][f]^2  (f64)
__global__ void k_rowsq(const float* __restrict__ feat, const double* __restrict__ A64,
                        const double* __restrict__ C64, double* __restrict__ sq) {
  int row = blockIdx.x, tid = threadIdx.x;
  const float* fr = feat + (size_t)row * Fn;
  double s = 0.0;
  for (int f = tid; f < Fn; f += 256) {
    double x = fma((double)fr[f], A64[f], C64[f]);
    s += x * x;
  }
  for (int o = 32; o > 0; o >>= 1) s += __shfl_down(s, o);
  __shared__ double red[4];
  if ((tid & 63) == 0) red[tid >> 6] = s;
  __syncthreads();
  if (tid == 0) sq[row] = red[0] + red[1] + red[2] + red[3];
}

// transpose + hi/lo split weights: W[K×N] f32 -> Wt[N×K] bf16 hi/lo
__global__ void k_wsplit(const float* __restrict__ W, int K, int N,
                         u16* __restrict__ Wth, u16* __restrict__ Wtl) {
  __shared__ float t[32][33];
  int k0 = blockIdx.y * 32, n0 = blockIdx.x * 32;
  int tx = threadIdx.x & 31, ty = threadIdx.x >> 5;  // ty 0..7
  for (int p = 0; p < 32; p += 8) {
    int k = k0 + ty + p, n = n0 + tx;
    t[ty + p][tx] = (k < K && n < N) ? W[(size_t)k * N + n] : 0.f;
  }
  __syncthreads();
  for (int p = 0; p < 32; p += 8) {
    int n = n0 + ty + p, k = k0 + tx;
    if (n < N && k < K) {
      float x = t[tx][ty + p];
      __hip_bfloat16 h = __float2bfloat16(x);
      float hf = __bfloat162float(h);
      __hip_bfloat16 lo = __float2bfloat16(x - hf);
      Wth[(size_t)n * K + k] = *reinterpret_cast<u16*>(&h);
      Wtl[(size_t)n * K + k] = *reinterpret_cast<u16*>(&lo);
    }
  }
}

// ---------- single-bf16 MFMA Gram, symmetric upper-triangle grid (528 blocks) ----------
// Each block (ti<=tj) computes X_ti · X_tj^T (128×128) and emits per-row top-8 candidates
// for BOTH tile ti's rows (row-side, slot tj*2+p) and tile tj's rows (col-side, slot ti*2+q).
// Epilogue in two 128×64 half-passes so LDS stays at 33 KB (4 blocks/CU).
__global__ __launch_bounds__(256) void k_gram(
    const u16* __restrict__ Ah, const double* __restrict__ sq, u64* __restrict__ part) {
  __shared__ union {
    u16 t[2][8192];        // A,B tiles: [kh*4096 + row*32 + col] elems, 16 KB each
    float c2[128 * 65];    // C half-tile (epilogue), 33.3 KB
  } lds;
  const int tid = threadIdx.x;
  const int w = tid >> 6, l = tid & 63;
  // XCD-aware swizzle (528 = 8*66) then triangle decode
  int swz = (blockIdx.x & 7) * 66 + (blockIdx.x >> 3);
  int rem = swz, ti = 0;
#pragma unroll 1
  while (rem >= 32 - ti) { rem -= 32 - ti; ti++; }
  const int tj = ti + rem;
  const int rA0 = ti * 128, rB0 = tj * 128;
  const int isDiag = (ti == tj);

  f32x4 acc[4][4];
  const f32x4 fz = {0.f, 0.f, 0.f, 0.f};
#pragma unroll
  for (int i = 0; i < 4; i++)
#pragma unroll
    for (int j = 0; j < 4; j++) acc[i][j] = fz;

  const u16* mats[2] = { Ah + (size_t)rA0 * Fn, Ah + (size_t)rB0 * Fn };

  // staging: 32 segs of 1024 B (2 matrices × 2 kh × 8 segs); seg covers 16 rows × 64 B
  auto stage = [&](int k0) {
#pragma unroll
    for (int q = 0; q < 8; q++) {
      int idx = w * 8 + q;
      int mm = idx >> 4, kh = (idx >> 3) & 1, s = idx & 7;
      int row = s * 16 + (l >> 2);
      int colel = ((l & 3) * 8) ^ ((row & 8) ? 16 : 0);
      gld16(mats[mm] + (size_t)row * Fn + k0 + kh * 32 + colel,
            (char*)&lds.t[mm][0] + kh * 8192 + s * 1024);
    }
  };

  const int swzr = (l & 8) ? 32 : 0;
  const int cB = ((l >> 4) * 16) ^ swzr;

  stage(0);
  const int NT = Fn / GBK;
  for (int kt = 0; kt < NT; kt++) {
    __syncthreads();
#pragma unroll
    for (int kh = 0; kh < 2; kh++) {
      short8 fa[4], fb[4];
#pragma unroll
      for (int i = 0; i < 4; i++) {
        int ar = (w >> 1) * 64 + i * 16 + (l & 15);
        fa[i] = *reinterpret_cast<const short8*>((const char*)&lds.t[0][0] + kh * 8192 + ar * 64 + cB);
        int br = (w & 1) * 64 + i * 16 + (l & 15);
        fb[i] = *reinterpret_cast<const short8*>((const char*)&lds.t[1][0] + kh * 8192 + br * 64 + cB);
      }
#pragma unroll
      for (int i = 0; i < 4; i++)
#pragma unroll
        for (int j = 0; j < 4; j++)
          acc[i][j] = __builtin_amdgcn_mfma_f32_16x16x32_bf16(fa[i], fb[j], acc[i][j], 0, 0, 0);
    }
    __syncthreads();
    if (kt + 1 < NT) stage((kt + 1) * GBK);
  }

  // epilogue: two passes over col halves p; C half in LDS [128 rows][65 f32]
  const int fr = l & 15, fq = l >> 4;
#pragma unroll 1
  for (int p = 0; p < 2; p++) {
    if ((w & 1) == p) {
#pragma unroll
      for (int i = 0; i < 4; i++) {
        int r0 = (w >> 1) * 64 + i * 16 + fq * 4;
#pragma unroll
        for (int j = 0; j < 4; j++) {
          int c0 = j * 16 + fr;
#pragma unroll
          for (int gg = 0; gg < 4; gg++)
            lds.c2[(r0 + gg) * 65 + c0] = acc[i][j][gg];
        }
      }
    }
    __syncthreads();
    u64 top[8];
#pragma unroll
    for (int k = 0; k < 8; k++) top[k] = ~0ull;
    int prow = -1, slot = 0;
    if (tid < 128) {
      // row-side: row tid of tile ti, scan 64 cols of tile tj (half p)
      int grow = rA0 + tid;
      float sqr = (float)sq[grow];
#pragma unroll 1
      for (int c = 0; c < 64; c++) {
        int gc = rB0 + p * 64 + c;
        if (gc == grow) continue;
        float gv = lds.c2[tid * 65 + c];
        float d2 = fmaxf(sqr + (float)sq[gc] - 2.f * gv, 0.f);
        u64 key = ((u64)__float_as_uint(d2) << 32) | (u32)gc;
        if (key < top[7]) {
          top[7] = key;
#pragma unroll
          for (int k = 7; k > 0; k--)
            if (top[k] < top[k - 1]) { u64 tmp = top[k]; top[k] = top[k - 1]; top[k - 1] = tmp; }
        }
      }
      prow = grow; slot = tj * 2 + p;
    } else if (!isDiag) {
      // col-side: col (p*64+cl) of tile tj, scan 64 rows of tile ti (half q)
      int idx = tid - 128, cl = idx >> 1, q = idx & 1;
      int gcol = rB0 + p * 64 + cl;
      float sqc = (float)sq[gcol];
#pragma unroll 1
      for (int s = 0; s < 64; s++) {
        int rr = q * 64 + s;
        float gv = lds.c2[rr * 65 + cl];
        int gr = rA0 + rr;
        float d2 = fmaxf(sqc + (float)sq[gr] - 2.f * gv, 0.f);
        u64 key = ((u64)__float_as_uint(d2) << 32) | (u32)gr;
        if (key < top[7]) {
          top[7] = key;
#pragma unroll
          for (int k = 7; k > 0; k--)
            if (top[k] < top[k - 1]) { u64 tmp = top[k]; top[k] = top[k - 1]; top[k - 1] = tmp; }
        }
      }
      prow = gcol; slot = ti * 2 + q;
    }
    if (prow >= 0) {
      u64* dst = part + ((size_t)prow * 64 + slot) * 8;
#pragma unroll
      for (int k = 0; k < 8; k++) dst[k] = top[k];
    }
    __syncthreads();
  }
}

// merge 512 partial candidates per row -> top-16 approx candidates
__global__ __launch_bounds__(256) void k_candmerge(const u64* __restrict__ part,
                                                   int* __restrict__ cand) {
  int row = blockIdx.x * 4 + (threadIdx.x >> 6);
  int l = threadIdx.x & 63;
  const u64* p = part + (size_t)row * 512 + (size_t)l * 8;
  u64 e[8];
#pragma unroll
  for (int k = 0; k < 8; k++) e[k] = p[k];
#pragma unroll 1
  for (int rnd = 0; rnd < 16; rnd++) {
    u64 m = e[0];
#pragma unroll
    for (int k = 1; k < 8; k++) m = e[k] < m ? e[k] : m;
#pragma unroll
    for (int off = 32; off; off >>= 1) {
      u64 o = __shfl_xor(m, off);
      m = o < m ? o : m;
    }
    if (l == 0) cand[row * 16 + rnd] = (int)(u32)m;
#pragma unroll
    for (int k = 0; k < 8; k++)
      if (e[k] == m) e[k] = ~0ull;
  }
}

// exact f64 re-rank of 16 candidates (+ noise tie-break) -> knn[row][7]; fused deg scatter
__global__ __launch_bounds__(256) void k_rerank(
    const float* __restrict__ feat, const double* __restrict__ A64,
    const double* __restrict__ C64, const double* __restrict__ sq,
    const float* __restrict__ noise, const int* __restrict__ cand,
    int* __restrict__ knn, float* __restrict__ deg) {
  int row = blockIdx.x;
  int w = threadIdx.x >> 6, l = threadIdx.x & 63;
  // xrow in registers: element l + 64*i
  double xr[Fn / 64];
  const float* fr = feat + (size_t)row * Fn;
#pragma unroll
  for (int i = 0; i < Fn / 64; i++) {
    int e = l + 64 * i;
    xr[i] = fma((double)fr[e], A64[e], C64[e]);
  }
  __shared__ double dots[16];
  for (int m = w; m < 16; m += 4) {
    int c = cand[row * 16 + m];
    const float* fc = feat + (size_t)c * Fn;
    double s = 0.0;
#pragma unroll
    for (int i = 0; i < Fn / 64; i++) {
      int e = l + 64 * i;
      double xj = fma((double)fc[e], A64[e], C64[e]);
      s = fma(xr[i], xj, s);
    }
#pragma unroll
    for (int off = 32; off; off >>= 1) s += __shfl_xor(s, off);
    if (l == 0) dots[m] = s;
  }
  __syncthreads();
  if (threadIdx.x == 0) {
    double sr = sq[row];
    double bd[Kn]; int bi7[Kn];
#pragma unroll
    for (int k = 0; k < Kn; k++) { bd[k] = 1e300; bi7[k] = 0; }
#pragma unroll 1
    for (int m = 0; m < 16; m++) {
      int c = cand[row * 16 + m];
      double d2 = sr + sq[c] - 2.0 * dots[m];
      d2 = d2 > 0.0 ? d2 : 0.0;
      double d = sqrt(d2) + (double)noise[(size_t)row * Bn + c] * 1e-6;
      if (d < bd[Kn - 1]) {
        bd[Kn - 1] = d; bi7[Kn - 1] = c;
#pragma unroll
        for (int k = Kn - 1; k > 0; k--)
          if (bd[k] < bd[k - 1]) {
            double td = bd[k]; bd[k] = bd[k - 1]; bd[k - 1] = td;
            int ti = bi7[k]; bi7[k] = bi7[k - 1]; bi7[k - 1] = ti;
          }
      }
    }
#pragma unroll
    for (int k = 0; k < Kn; k++) {
      knn[row * Kn + k] = bi7[k];
      atomicAdd(&deg[bi7[k]], 1.f);   // exact: integer-valued f32 adds
    }
  }
}

// ---------- degree / dinv ----------
__global__ void k_deginit(float* __restrict__ deg) {
  int i = blockIdx.x * 256 + threadIdx.x;
  if (i < Bn) deg[i] = 1.f;   // self loop
}
__global__ void k_dinv(const float* __restrict__ deg, float* __restrict__ dinv) {
  int i = blockIdx.x * 256 + threadIdx.x;
  if (i < Bn) dinv[i] = rsqrtf(deg[i]);
}

// ---------- GCN scatter ----------
__global__ void k_aggsc(const float* __restrict__ h, const int* __restrict__ knn,
                        const float* __restrict__ dinv, float* __restrict__ out) {
  int s = blockIdx.x, f = threadIdx.x;
  float hv = h[(size_t)s * Hn + f] * dinv[s];
#pragma unroll
  for (int k = 0; k < Kn; k++) {
    int t = knn[s * Kn + k];
    atomicAdd(&out[(size_t)t * Hn + f], dinv[t] * hv);
  }
}

// BN (+relu) then hi/lo bf16 split; 8 elems/thread
__global__ void k_bnact_split(const float* __restrict__ x, const float* __restrict__ g,
                              const float* __restrict__ b, const float* __restrict__ m,
                              const float* __restrict__ v, int relu,
                              u16* __restrict__ oh, u16* __restrict__ ol) {
  size_t i8 = ((size_t)blockIdx.x * 256 + threadIdx.x) * 8;
  int c0 = (int)(i8 & (Hn - 1));
  float4 a = *reinterpret_cast<const float4*>(x + i8);
  float4 bb = *reinterpret_cast<const float4*>(x + i8 + 4);
  float xs[8] = {a.x, a.y, a.z, a.w, bb.x, bb.y, bb.z, bb.w};
  short8 hv, lv;
#pragma unroll
  for (int k = 0; k < 8; k++) {
    int c = c0 + k;
    float val = (xs[k] - m[c]) * rsqrtf(v[c] + 1e-5f) * g[c] + b[c];
    if (relu) val = fmaxf(val, 0.f);
    __hip_bfloat16 h = __float2bfloat16(val);
    float hf = __bfloat162float(h);
    __hip_bfloat16 lo = __float2bfloat16(val - hf);
    hv[k] = (short)*reinterpret_cast<u16*>(&h);
    lv[k] = (short)*reinterpret_cast<u16*>(&lo);
  }
  *reinterpret_cast<short8*>(oh + i8) = hv;
  *reinterpret_cast<short8*>(ol + i8) = lv;
}

// ---------- bf16-split MFMA GEMM: C[M×N] f32 = [A1|A2] @ W  (W given as Wt[N×K] hi/lo)
// 64x64 tile, BK=64, k-major LDS (64-row tiles -> 1024B per k-chunk).
// ep: 0 none, 1 +bias, 2 +bias+relu, 3 dual-write (C=h raw, C2=dinv²·h+bias)
__global__ __launch_bounds__(256) void k_mgemm(
    const u16* __restrict__ Ah1, const u16* __restrict__ Al1, int lda1,
    const u16* __restrict__ Ah2, const u16* __restrict__ Al2, int lda2, int Ksplit,
    const u16* __restrict__ Wth, const u16* __restrict__ Wtl,
    const float* __restrict__ bias, float* __restrict__ C, int N, int K, int ep,
    float* __restrict__ C2, const float* __restrict__ dinvp) {
  __shared__ u16 tA[2][4096];   // [8 kq][64 row][16B], hi/lo
  __shared__ u16 tB[2][4096];
  const int tid = threadIdx.x;
  const int w = tid >> 6, l = tid & 63;
  const int m0 = blockIdx.y * 64, n0 = blockIdx.x * 64;
  const int fr = l & 15, fq = l >> 4;

  f32x4 acc[2][2];
  const f32x4 fz = {0.f, 0.f, 0.f, 0.f};
#pragma unroll
  for (int i = 0; i < 2; i++)
#pragma unroll
    for (int j = 0; j < 2; j++) acc[i][j] = fz;

  auto stage = [&](int k0) {
#pragma unroll
    for (int q = 0; q < 2; q++) {
      int s = w * 2 + q;            // kq 0..7
      int kg = k0 + s * 8;
      const u16* ah; const u16* al; int ld; int kk = kg;
      if (kg < Ksplit) { ah = Ah1; al = Al1; ld = lda1; }
      else             { ah = Ah2; al = Al2; ld = lda2; kk = kg - Ksplit; }
      gld16(ah + (size_t)(m0 + l) * ld + kk, (char*)&tA[0][0] + s * 1024);
      gld16(al + (size_t)(m0 + l) * ld + kk, (char*)&tA[1][0] + s * 1024);
      gld16(Wth + (size_t)(n0 + l) * K + kg, (char*)&tB[0][0] + s * 1024);
      gld16(Wtl + (size_t)(n0 + l) * K + kg, (char*)&tB[1][0] + s * 1024);
    }
  };

  stage(0);
  const int NT = K / GBK;
  for (int kt = 0; kt < NT; kt++) {
    __syncthreads();
#pragma unroll
    for (int kh = 0; kh < 2; kh++) {
      const int kb = (kh * 4 + fq) * 1024;   // 64 rows/tile -> 1024B per k-chunk
      short8 fa[2][2], fb[2][2];
#pragma unroll
      for (int i = 0; i < 2; i++) {
        int ar = (w >> 1) * 32 + i * 16 + fr;
        fa[0][i] = *reinterpret_cast<const short8*>((const char*)&tA[0][0] + kb + ar * 16);
        fa[1][i] = *reinterpret_cast<const short8*>((const char*)&tA[1][0] + kb + ar * 16);
        int br = (w & 1) * 32 + i * 16 + fr;
        fb[0][i] = *reinterpret_cast<const short8*>((const char*)&tB[0][0] + kb + br * 16);
        fb[1][i] = *reinterpret_cast<const short8*>((const char*)&tB[1][0] + kb + br * 16);
      }
#pragma unroll
      for (int i = 0; i < 2; i++)
#pragma unroll
        for (int j = 0; j < 2; j++) {
          acc[i][j] = __builtin_amdgcn_mfma_f32_16x16x32_bf16(fa[1][i], fb[0][j], acc[i][j], 0, 0, 0);
          acc[i][j] = __builtin_amdgcn_mfma_f32_16x16x32_bf16(fa[0][i], fb[1][j], acc[i][j], 0, 0, 0);
          acc[i][j] = __builtin_amdgcn_mfma_f32_16x16x32_bf16(fa[0][i], fb[0][j], acc[i][j], 0, 0, 0);
        }
    }
    __syncthreads();
    if (kt + 1 < NT) stage((kt + 1) * GBK);
  }

#pragma unroll
  for (int i = 0; i < 2; i++) {
    int rg0 = m0 + (w >> 1) * 32 + i * 16 + fq * 4;
#pragma unroll
    for (int j = 0; j < 2; j++) {
      int cg = n0 + (w & 1) * 32 + j * 16 + fr;
      float bv = (ep >= 1) ? bias[cg] : 0.f;
#pragma unroll
      for (int g = 0; g < 4; g++) {
        float raw = acc[i][j][g];
        size_t idx = (size_t)(rg0 + g) * N + cg;
        if (ep == 3) {
          float di = dinvp[rg0 + g];
          C[idx] = raw;
          C2[idx] = di * di * raw + bv;
        } else {
          float val = raw + bv;
          if (ep == 2) val = fmaxf(val, 0.f);
          C[idx] = val;
        }
      }
    }
  }
}

// ---------- f32 GEMM (tiny classifier2 only) ----------
__global__ __launch_bounds__(256) void k_gemm(
    const float* __restrict__ A1, int lda1,
    const float* __restrict__ Bw, const float* __restrict__ bias,
    float* __restrict__ C, int M, int N, int K, int ep) {
  __shared__ float As[16][65];
  __shared__ float Bs[16][64];
  int tid = threadIdx.x;
  int n0 = blockIdx.x * 64;
  int row0 = blockIdx.y * 64;
  int tx = tid & 15, ty = tid >> 4;
  float acc[4][4] = {};
  for (int k0 = 0; k0 < K; k0 += 16) {
    int kk = tid & 15, mi = tid >> 4;
#pragma unroll
    for (int p = 0; p < 4; p++) {
      int row = row0 + mi + p * 16;
      As[kk][mi + p * 16] = A1[(size_t)row * lda1 + k0 + kk];
    }
    int nj = tid & 63, kq = tid >> 6;
#pragma unroll
    for (int p = 0; p < 4; p++) {
      int kb = kq + p * 4;
      int n = n0 + nj;
      Bs[kb][nj] = (n < N) ? Bw[(size_t)(k0 + kb) * N + n] : 0.f;
    }
    __syncthreads();
#pragma unroll
    for (int kk2 = 0; kk2 < 16; kk2++) {
      float a[4], b[4];
#pragma unroll
      for (int i = 0; i < 4; i++) a[i] = As[kk2][ty * 4 + i];
#pragma unroll
      for (int j = 0; j < 4; j++) b[j] = Bs[kk2][tx * 4 + j];
#pragma unroll
      for (int i = 0; i < 4; i++)
#pragma unroll
        for (int j = 0; j < 4; j++) acc[i][j] += a[i] * b[j];
    }
    __syncthreads();
  }
#pragma unroll
  for (int i = 0; i < 4; i++) {
    int row = row0 + ty * 4 + i;
#pragma unroll
    for (int j = 0; j < 4; j++) {
      int n = n0 + tx * 4 + j;
      if (n < N) {
        float v = acc[i][j];
        if (ep >= 1) v += bias[n];
        if (ep == 2) v = fmaxf(v, 0.f);
        C[(size_t)row * N + n] = v;
      }
    }
  }
}

extern "C" void kernel_launch(void* const* d_in, const int* in_sizes, int n_in,
                              void* d_out, int out_size, void* d_ws, size_t ws_size,
                              hipStream_t stream) {
  const float* feat  = (const float*)d_in[0];
  const float* noise = (const float*)d_in[1];
  const float* bnf_g = (const float*)d_in[2];
  const float* bnf_b = (const float*)d_in[3];
  const float* bnf_m = (const float*)d_in[4];
  const float* bnf_v = (const float*)d_in[5];
  const float* W1 = (const float*)d_in[6];
  const float* b1 = (const float*)d_in[7];
  const float* W2 = (const float*)d_in[8];
  const float* b2 = (const float*)d_in[9];
  const float* W3 = (const float*)d_in[10];
  const float* b3 = (const float*)d_in[11];
  const float* bn1_g = (const float*)d_in[12];
  const float* bn1_b = (const float*)d_in[13];
  const float* bn1_m = (const float*)d_in[14];
  const float* bn1_v = (const float*)d_in[15];
  const float* bn2_g = (const float*)d_in[16];
  const float* bn2_b = (const float*)d_in[17];
  const float* bn2_m = (const float*)d_in[18];
  const float* bn2_v = (const float*)d_in[19];
  const float* bn3_g = (const float*)d_in[20];
  const float* bn3_b = (const float*)d_in[21];
  const float* bn3_m = (const float*)d_in[22];
  const float* bn3_v = (const float*)d_in[23];
  const float* Wc1 = (const float*)d_in[24];
  const float* bc1 = (const float*)d_in[25];
  const float* Wc2 = (const float*)d_in[26];
  const float* bc2 = (const float*)d_in[27];
  float* outp = (float*)d_out;

  char* w = (char*)d_ws;
  size_t off = 0;
  auto alloc = [&](size_t n) { void* p = w + off; off = (off + n + 255) & ~(size_t)255; return p; };
  u16*    Ahb  = (u16*)   alloc((size_t)Bn * Fn * 2);
  u16*    Alb  = (u16*)   alloc((size_t)Bn * Fn * 2);
  double* A64  = (double*)alloc(Fn * 8);
  double* C64  = (double*)alloc(Fn * 8);
  double* sq   = (double*)alloc(Bn * 8);
  u64*    part = (u64*)   alloc((size_t)Bn * 64 * 8 * 8);
  int*    cand = (int*)   alloc((size_t)Bn * 16 * 4);
  int*    knn  = (int*)   alloc((size_t)Bn * Kn * 4);
  float*  deg  = (float*) alloc(Bn * 4);
  float*  dinv = (float*) alloc(Bn * 4);
  float*  g1   = (float*) alloc((size_t)Bn * Hn * 4);
  float*  g2   = (float*) alloc((size_t)Bn * Hn * 4);
  float*  hid  = (float*) alloc((size_t)Bn * 128 * 4);
  u16*    sh   = (u16*)   alloc((size_t)Bn * Hn * 2);
  u16*    sl   = (u16*)   alloc((size_t)Bn * Hn * 2);
  u16*    W1th = (u16*)   alloc((size_t)Fn * Hn * 2);
  u16*    W1tl = (u16*)   alloc((size_t)Fn * Hn * 2);
  u16*    W2th = (u16*)   alloc((size_t)Hn * Hn * 2);
  u16*    W2tl = (u16*)   alloc((size_t)Hn * Hn * 2);
  u16*    W3th = (u16*)   alloc((size_t)Hn * Hn * 2);
  u16*    W3tl = (u16*)   alloc((size_t)Hn * Hn * 2);
  u16*    Wc1th= (u16*)   alloc((size_t)(Hn + Fn) * 128 * 2);
  u16*    Wc1tl= (u16*)   alloc((size_t)(Hn + Fn) * 128 * 2);
  (void)ws_size; (void)in_sizes; (void)n_in; (void)out_size;

  k_prep<<<(Fn + 255) / 256, 256, 0, stream>>>(bnf_g, bnf_b, bnf_m, bnf_v, A64, C64);
  k_bnsplit<<<Bn, Fn / 8, 0, stream>>>(feat, A64, C64, Ahb, Alb);
  k_rowsq<<<Bn, 256, 0, stream>>>(feat, A64, C64, sq);
  k_wsplit<<<dim3(Hn / 32, Fn / 32), 256, 0, stream>>>(W1, Fn, Hn, W1th, W1tl);
  k_wsplit<<<dim3(Hn / 32, Hn / 32), 256, 0, stream>>>(W2, Hn, Hn, W2th, W2tl);
  k_wsplit<<<dim3(Hn / 32, Hn / 32), 256, 0, stream>>>(W3, Hn, Hn, W3th, W3tl);
  k_wsplit<<<dim3(128 / 32, (Hn + Fn) / 32), 256, 0, stream>>>(Wc1, Hn + Fn, 128, Wc1th, Wc1tl);

  k_gram<<<528, 256, 0, stream>>>(Ahb, sq, part);
  k_candmerge<<<Bn / 4, 256, 0, stream>>>(part, cand);
  k_deginit<<<(Bn + 255) / 256, 256, 0, stream>>>(deg);
  k_rerank<<<Bn, 256, 0, stream>>>(feat, A64, C64, sq, noise, cand, knn, deg);
  k_dinv<<<(Bn + 255) / 256, 256, 0, stream>>>(deg, dinv);

  dim3 gm(Hn / 64, Bn / 64);
  // layer 1 (ep=3: g1 = h, g2 = di²h + b1)
  k_mgemm<<<gm, 256, 0, stream>>>(Ahb, Alb, Fn, Ahb, Alb, Fn, Fn, W1th, W1tl, b1, g1, Hn, Fn, 3, g2, dinv);
  k_aggsc<<<Bn, Hn, 0, stream>>>(g1, knn, dinv, g2);
  k_bnact_split<<<(Bn * Hn) / (256 * 8), 256, 0, stream>>>(g2, bn1_g, bn1_b, bn1_m, bn1_v, 1, sh, sl);
  // layer 2
  k_mgemm<<<gm, 256, 0, stream>>>(sh, sl, Hn, sh, sl, Hn, Hn, W2th, W2tl, b2, g1, Hn, Hn, 3, g2, dinv);
  k_aggsc<<<Bn, Hn, 0, stream>>>(g1, knn, dinv, g2);
  k_bnact_split<<<(Bn * Hn) / (256 * 8), 256, 0, stream>>>(g2, bn2_g, bn2_b, bn2_m, bn2_v, 1, sh, sl);
  // layer 3
  k_mgemm<<<gm, 256, 0, stream>>>(sh, sl, Hn, sh, sl, Hn, Hn, W3th, W3tl, b3, g1, Hn, Hn, 3, g2, dinv);
  k_aggsc<<<Bn, Hn, 0, stream>>>(g1, knn, dinv, g2);
  k_bnact_split<<<(Bn * Hn) / (256 * 8), 256, 0, stream>>>(g2, bn3_g, bn3_b, bn3_m, bn3_v, 0, sh, sl);
  // classifier1: comb = [h3 | x] in bf16 splits
  k_mgemm<<<dim3(128 / 64, Bn / 64), 256, 0, stream>>>(sh, sl, Hn, Ahb, Alb, Fn, Hn,
                                                       Wc1th, Wc1tl, bc1, hid, 128, Hn + Fn, 2,
                                                       nullptr, nullptr);
  // classifier2 (tiny, f32)
  k_gemm<<<dim3(1, Bn / 64), 256, 0, stream>>>(hid, 128, Wc2, bc2, outp, Bn, Cn, 128, 1);
}